// Round 1
// baseline (1315.188 us; speedup 1.0000x reference)
//
#include <hip/hip_runtime.h>
#include <math.h>

typedef __attribute__((ext_vector_type(4))) float f32x4;
typedef __attribute__((ext_vector_type(8))) short s16x8;
typedef __attribute__((ext_vector_type(8))) unsigned short u16x8;
typedef __attribute__((ext_vector_type(4))) unsigned short u16x4;

#define DI __device__ __forceinline__

DI unsigned short f2bf(float f) {
  unsigned int u = __builtin_bit_cast(unsigned int, f);
  u = u + 0x7fffu + ((u >> 16) & 1u);
  return (unsigned short)(u >> 16);
}

// ---------------- weight fp32 -> bf16 (with layer-strided packing) ----------------
__global__ __launch_bounds__(256) void cvtw_k(const float* __restrict__ src,
    unsigned short* __restrict__ dst, int chunk, int dstStride, int total4)
{
  for (int i = blockIdx.x * 256 + threadIdx.x; i < total4; i += gridDim.x * 256) {
    int idx = i * 4;
    int blk = idx / chunk, off = idx - blk * chunk;   // chunk is a power of 2
    f32x4 v = *reinterpret_cast<const f32x4*>(src + idx);
    u16x4 o = { f2bf(v[0]), f2bf(v[1]), f2bf(v[2]), f2bf(v[3]) };
    *reinterpret_cast<u16x4*>(dst + (size_t)blk * dstStride + off) = o;
  }
}

// ---------------- x -> xf (f32 master) + xb (bf16 mirror) ----------------
__global__ __launch_bounds__(256) void xinit_k(const float* __restrict__ x,
    float* __restrict__ xf, unsigned short* __restrict__ xb, int n4)
{
  for (int i = blockIdx.x * 256 + threadIdx.x; i < n4; i += gridDim.x * 256) {
    f32x4 v = *reinterpret_cast<const f32x4*>(x + (size_t)i * 4);
    *reinterpret_cast<f32x4*>(xf + (size_t)i * 4) = v;
    u16x4 o = { f2bf(v[0]), f2bf(v[1]), f2bf(v[2]), f2bf(v[3]) };
    *reinterpret_cast<u16x4*>(xb + (size_t)i * 4) = o;
  }
}

// ---------------- Ebar[j,d] = mean_{t=1023-j}^{2046-j} rel[t,d] ----------------
__global__ __launch_bounds__(64) void ebar_k(const float* __restrict__ rel,
    float* __restrict__ ebar)
{
  int j = blockIdx.x, d = threadIdx.x;
  const float* p = rel + (size_t)(1023 - j) * 64 + d;
  float s = 0.f;
  for (int k = 0; k < 1024; ++k) s += p[(size_t)k * 64];
  ebar[j * 64 + d] = s * (1.f / 1024.f);
}

// ---------------- GEMM: C[m,n] = sum_k A[m,k]*B[n,k] + bias, fused epilogues ----
// BF32=0: B is bf16 (preconverted); BF32=1: B is fp32 (converted during staging).
// mode 0: fused QKV (N=3072, per-block qtype from n0)
// mode 1/2/3: Q / K' / V only (fallback)
// mode 4: fp32 out -> yf  (O-proj, FFN2)
// mode 5: gelu bf16 out -> hb (FFN1)
template<int BF32>
__global__ __launch_bounds__(256) void gemm_k(
    const unsigned short* __restrict__ A, const void* __restrict__ Bp,
    int K, int N, int mode,
    const float* __restrict__ bias0, const float* __restrict__ bias1,
    const float* __restrict__ bias2, const float* __restrict__ ebar,
    unsigned short* __restrict__ qb, unsigned short* __restrict__ kb,
    unsigned short* __restrict__ vtb, float* __restrict__ yf,
    unsigned short* __restrict__ hb)
{
  __shared__ __align__(16) unsigned short SM[2 * 128 * 72];
  auto As = reinterpret_cast<unsigned short(*)[72]>(SM);
  auto Bs = reinterpret_cast<unsigned short(*)[72]>(SM + 128 * 72);
  const int tid = threadIdx.x, l = tid & 63, w = tid >> 6;
  const int wr = w >> 1, wc = w & 1, lr = l & 15, lg = l >> 4;
  const int m0 = blockIdx.y * 128, n0 = blockIdx.x * 128;
  f32x4 acc[4][4];
#pragma unroll
  for (int i = 0; i < 4; ++i)
#pragma unroll
    for (int j = 0; j < 4; ++j) acc[i][j] = f32x4{0.f, 0.f, 0.f, 0.f};

  for (int k0 = 0; k0 < K; k0 += 64) {
    __syncthreads();
#pragma unroll
    for (int it = 0; it < 4; ++it) {
      int lin = (it * 256 + tid) * 8, r = lin >> 6, c = lin & 63;
      *reinterpret_cast<u16x8*>(&As[r][c]) =
          *reinterpret_cast<const u16x8*>(A + (size_t)(m0 + r) * K + k0 + c);
    }
    if (BF32 == 0) {
      const unsigned short* Bb = (const unsigned short*)Bp;
#pragma unroll
      for (int it = 0; it < 4; ++it) {
        int lin = (it * 256 + tid) * 8, r = lin >> 6, c = lin & 63;
        *reinterpret_cast<u16x8*>(&Bs[r][c]) =
            *reinterpret_cast<const u16x8*>(Bb + (size_t)(n0 + r) * K + k0 + c);
      }
    } else {
      const float* Bf = (const float*)Bp;
#pragma unroll
      for (int it = 0; it < 8; ++it) {
        int lin = (it * 256 + tid) * 4, r = lin >> 6, c = lin & 63;
        f32x4 v = *reinterpret_cast<const f32x4*>(Bf + (size_t)(n0 + r) * K + k0 + c);
        u16x4 o = { f2bf(v[0]), f2bf(v[1]), f2bf(v[2]), f2bf(v[3]) };
        *reinterpret_cast<u16x4*>(&Bs[r][c]) = o;
      }
    }
    __syncthreads();
#pragma unroll
    for (int kk = 0; kk < 2; ++kk) {
      s16x8 af[4], bfr[4];
#pragma unroll
      for (int mi = 0; mi < 4; ++mi)
        af[mi] = *reinterpret_cast<const s16x8*>(&As[wr * 64 + mi * 16 + lr][kk * 32 + lg * 8]);
#pragma unroll
      for (int ni = 0; ni < 4; ++ni)
        bfr[ni] = *reinterpret_cast<const s16x8*>(&Bs[wc * 64 + ni * 16 + lr][kk * 32 + lg * 8]);
#pragma unroll
      for (int mi = 0; mi < 4; ++mi)
#pragma unroll
        for (int ni = 0; ni < 4; ++ni)
          acc[mi][ni] = __builtin_amdgcn_mfma_f32_16x16x32_bf16(af[mi], bfr[ni], acc[mi][ni], 0, 0, 0);
    }
  }

  if (mode <= 3) {
    int qtype, nbase;
    const float* bias;
    if (mode == 0) {
      qtype = n0 >> 10; nbase = n0 & 1023;
      bias = qtype == 0 ? bias0 : (qtype == 1 ? bias1 : bias2);
    } else { qtype = mode - 1; nbase = n0; bias = bias0; }
    if (qtype < 2) {
      unsigned short* dst = (qtype == 0) ? qb : kb;
#pragma unroll
      for (int mi = 0; mi < 4; ++mi)
#pragma unroll
        for (int ni = 0; ni < 4; ++ni) {
          int nin = nbase + wc * 64 + ni * 16 + lr;
          int hh = nin >> 6, dh = nin & 63;
          float bv = bias[nin];
#pragma unroll
          for (int rr = 0; rr < 4; ++rr) {
            int m = m0 + wr * 64 + mi * 16 + lg * 4 + rr;
            int b = m >> 10, s = m & 1023;
            float v = acc[mi][ni][rr] + bv;
            if (qtype == 1) v = v * 0.125f + ebar[s * 64 + dh];
            dst[(size_t)(b * 16 + hh) * 65536 + (size_t)s * 64 + dh] = f2bf(v);
          }
        }
    } else {
      // V: transpose-bounce through LDS, write vtb[B,H,HD,S] coalesced
      auto T = reinterpret_cast<unsigned short(*)[136]>(SM);
      __syncthreads();
#pragma unroll
      for (int mi = 0; mi < 4; ++mi)
#pragma unroll
        for (int ni = 0; ni < 4; ++ni) {
          int nl = wc * 64 + ni * 16 + lr;
          float bv = bias[nbase + nl];
#pragma unroll
          for (int rr = 0; rr < 4; ++rr) {
            int ml = wr * 64 + mi * 16 + lg * 4 + rr;
            T[ml][nl] = f2bf(acc[mi][ni][rr] + bv);
          }
        }
      __syncthreads();
      int b = m0 >> 10, j0 = m0 & 1023;
#pragma unroll
      for (int lp = 0; lp < 8; ++lp) {
        int dl = lp * 16 + (tid >> 4), jc = (tid & 15) * 8;
        u16x8 o;
#pragma unroll
        for (int e = 0; e < 8; ++e) o[e] = T[jc + e][dl];
        int nin = nbase + dl, hh = nin >> 6, dh = nin & 63;
        *reinterpret_cast<u16x8*>(vtb + (size_t)(b * 16 + hh) * 65536 + (size_t)dh * 1024 + j0 + jc) = o;
      }
    }
  } else {
#pragma unroll
    for (int mi = 0; mi < 4; ++mi)
#pragma unroll
      for (int ni = 0; ni < 4; ++ni) {
        int nn = n0 + wc * 64 + ni * 16 + lr;
        float bv = bias0[nn];
#pragma unroll
        for (int rr = 0; rr < 4; ++rr) {
          int m = m0 + wr * 64 + mi * 16 + lg * 4 + rr;
          float v = acc[mi][ni][rr] + bv;
          if (mode == 4) yf[(size_t)m * N + nn] = v;
          else hb[(size_t)m * N + nn] = f2bf(0.5f * v * (1.f + erff(v * 0.70710678118654752f)));
        }
      }
  }
}

// ---------------- flash attention: softmax(Q K'^T) V ----------------
__global__ __launch_bounds__(256) void attn_k(const unsigned short* __restrict__ qb,
    const unsigned short* __restrict__ kb, const unsigned short* __restrict__ vtb,
    unsigned short* __restrict__ ctx)
{
  __shared__ __align__(16) unsigned short Ks[64][72];
  __shared__ __align__(16) unsigned short Vts[64][72];
  __shared__ __align__(16) unsigned short Pl[4][16][72];
  const int tq = blockIdx.x, bh = blockIdx.y;
  const int tid = threadIdx.x, l = tid & 63, w = tid >> 6;
  const int lr = l & 15, lg = l >> 4;

  const unsigned short* Qp = qb + (size_t)bh * 65536 + (size_t)(tq * 64 + w * 16 + lr) * 64 + lg * 8;
  s16x8 qf[2];
  qf[0] = *reinterpret_cast<const s16x8*>(Qp);
  qf[1] = *reinterpret_cast<const s16x8*>(Qp + 32);

  f32x4 oacc[4];
#pragma unroll
  for (int di = 0; di < 4; ++di) oacc[di] = f32x4{0.f, 0.f, 0.f, 0.f};
  float M[4] = { -1e30f, -1e30f, -1e30f, -1e30f };
  float L[4] = { 0.f, 0.f, 0.f, 0.f };

  for (int jt = 0; jt < 16; ++jt) {
    __syncthreads();
#pragma unroll
    for (int it = 0; it < 2; ++it) {
      int lin = (it * 256 + tid) * 8, r = lin >> 6, c = lin & 63;
      *reinterpret_cast<u16x8*>(&Ks[r][c]) =
          *reinterpret_cast<const u16x8*>(kb + (size_t)bh * 65536 + (size_t)(jt * 64 + r) * 64 + c);
      *reinterpret_cast<u16x8*>(&Vts[r][c]) =
          *reinterpret_cast<const u16x8*>(vtb + (size_t)bh * 65536 + (size_t)r * 1024 + jt * 64 + c);
    }
    __syncthreads();

    f32x4 sacc[4];
#pragma unroll
    for (int ni = 0; ni < 4; ++ni) sacc[ni] = f32x4{0.f, 0.f, 0.f, 0.f};
#pragma unroll
    for (int kk = 0; kk < 2; ++kk) {
#pragma unroll
      for (int ni = 0; ni < 4; ++ni) {
        s16x8 kf = *reinterpret_cast<const s16x8*>(&Ks[ni * 16 + lr][kk * 32 + lg * 8]);
        sacc[ni] = __builtin_amdgcn_mfma_f32_16x16x32_bf16(qf[kk], kf, sacc[ni], 0, 0, 0);
      }
    }
#pragma unroll
    for (int r = 0; r < 4; ++r) {
      float pm = fmaxf(fmaxf(sacc[0][r], sacc[1][r]), fmaxf(sacc[2][r], sacc[3][r]));
#pragma unroll
      for (int xm = 1; xm < 16; xm <<= 1) pm = fmaxf(pm, __shfl_xor(pm, xm));
      float mn = fmaxf(M[r], pm);
      float sc = expf(M[r] - mn);
      float rs = 0.f;
#pragma unroll
      for (int ni = 0; ni < 4; ++ni) { float p = expf(sacc[ni][r] - mn); sacc[ni][r] = p; rs += p; }
#pragma unroll
      for (int xm = 1; xm < 16; xm <<= 1) rs += __shfl_xor(rs, xm);
      M[r] = mn; L[r] = L[r] * sc + rs;
#pragma unroll
      for (int di = 0; di < 4; ++di) oacc[di][r] *= sc;
#pragma unroll
      for (int ni = 0; ni < 4; ++ni) Pl[w][lg * 4 + r][ni * 16 + lr] = f2bf(sacc[ni][r]);
    }
    __syncthreads();
#pragma unroll
    for (int kk = 0; kk < 2; ++kk) {
      s16x8 pa = *reinterpret_cast<const s16x8*>(&Pl[w][lr][kk * 32 + lg * 8]);
#pragma unroll
      for (int di = 0; di < 4; ++di) {
        s16x8 vf = *reinterpret_cast<const s16x8*>(&Vts[di * 16 + lr][kk * 32 + lg * 8]);
        oacc[di] = __builtin_amdgcn_mfma_f32_16x16x32_bf16(pa, vf, oacc[di], 0, 0, 0);
      }
    }
  }
  const int b = bh >> 4, hh = bh & 15;
#pragma unroll
  for (int r = 0; r < 4; ++r) {
    float inv = 1.f / L[r];
    int qrow = tq * 64 + w * 16 + lg * 4 + r;
#pragma unroll
    for (int di = 0; di < 4; ++di)
      ctx[(size_t)(b * 1024 + qrow) * 1024 + hh * 64 + di * 16 + lr] = f2bf(oacc[di][r] * inv);
  }
}

// ---------------- LayerNorm(xf + yf) -> outf (f32) + outb (bf16) ----------------
__global__ __launch_bounds__(256) void ln_k(const float* __restrict__ xf,
    const float* __restrict__ yf, const float* __restrict__ g,
    const float* __restrict__ be, float* __restrict__ outf,
    unsigned short* __restrict__ outb)
{
  int row = blockIdx.x, tid = threadIdx.x, l = tid & 63, w = tid >> 6;
  size_t base = (size_t)row * 1024 + tid * 4;
  f32x4 v = *reinterpret_cast<const f32x4*>(xf + base);
  f32x4 yv = *reinterpret_cast<const f32x4*>(yf + base);
  v = v + yv;
  float s = v[0] + v[1] + v[2] + v[3];
  float q = v[0] * v[0] + v[1] * v[1] + v[2] * v[2] + v[3] * v[3];
#pragma unroll
  for (int off = 1; off < 64; off <<= 1) { s += __shfl_xor(s, off); q += __shfl_xor(q, off); }
  __shared__ float ss[4], qq[4];
  if (l == 0) { ss[w] = s; qq[w] = q; }
  __syncthreads();
  s = ss[0] + ss[1] + ss[2] + ss[3];
  q = qq[0] + qq[1] + qq[2] + qq[3];
  float m = s * (1.f / 1024.f);
  float var = q * (1.f / 1024.f) - m * m;
  float rs = rsqrtf(var + 1e-5f);
  f32x4 gv = *reinterpret_cast<const f32x4*>(g + tid * 4);
  f32x4 bv = *reinterpret_cast<const f32x4*>(be + tid * 4);
  f32x4 o; u16x4 ob;
#pragma unroll
  for (int e = 0; e < 4; ++e) { o[e] = (v[e] - m) * rs * gv[e] + bv[e]; ob[e] = f2bf(o[e]); }
  *reinterpret_cast<f32x4*>(outf + base) = o;
  *reinterpret_cast<u16x4*>(outb + base) = ob;
}

// ---------------- host ----------------
extern "C" void kernel_launch(void* const* d_in, const int* in_sizes, int n_in,
                              void* d_out, int out_size, void* d_ws, size_t ws_size,
                              hipStream_t stream)
{
  (void)in_sizes; (void)n_in; (void)out_size;
  const float* x   = (const float*)d_in[0];
  const float* Wq  = (const float*)d_in[1];
  const float* bq  = (const float*)d_in[2];
  const float* Wk  = (const float*)d_in[3];
  const float* bk  = (const float*)d_in[4];
  const float* Wv  = (const float*)d_in[5];
  const float* bv  = (const float*)d_in[6];
  const float* Wo  = (const float*)d_in[7];
  const float* bo  = (const float*)d_in[8];
  const float* rel = (const float*)d_in[9];
  const float* W1  = (const float*)d_in[10];
  const float* b1  = (const float*)d_in[11];
  const float* W2  = (const float*)d_in[12];
  const float* b2  = (const float*)d_in[13];
  const float* g1  = (const float*)d_in[14];
  const float* be1 = (const float*)d_in[15];
  const float* g2  = (const float*)d_in[16];
  const float* be2 = (const float*)d_in[17];
  float* out = (float*)d_out;
  char* ws = (char*)d_ws;

  const size_t OFF_XF = 0, OFF_YF = 8388608, OFF_XB = 16777216, OFF_QB = 20971520,
      OFF_KB = 25165824, OFF_VT = 29360128, OFF_CT = 33554432, OFF_HB = 37748736,
      OFF_EB = 54525952, OFF_WQKV = 54788096, OFF_WO = 79953920, OFF_W1 = 88342528,
      OFF_W2 = 121896960, NEED = 155451392;

  float* xf = (float*)(ws + OFF_XF);
  float* yf = (float*)(ws + OFF_YF);
  unsigned short* xb  = (unsigned short*)(ws + OFF_XB);
  unsigned short* qbp = (unsigned short*)(ws + OFF_QB);
  unsigned short* kbp = (unsigned short*)(ws + OFF_KB);
  unsigned short* vtp = (unsigned short*)(ws + OFF_VT);
  unsigned short* ctx = (unsigned short*)(ws + OFF_CT);
  unsigned short* hb  = (unsigned short*)(ws + OFF_HB);
  float* ebar = (float*)(ws + OFF_EB);
  unsigned short* wqkv = (unsigned short*)(ws + OFF_WQKV);
  unsigned short* wob  = (unsigned short*)(ws + OFF_WO);
  unsigned short* w1b  = (unsigned short*)(ws + OFF_W1);
  unsigned short* w2b  = (unsigned short*)(ws + OFF_W2);

  const bool preconv = ws_size >= NEED;
  if (preconv) {
    cvtw_k<<<2048, 256, 0, stream>>>(Wq, wqkv,           1048576, 3145728, 1048576);
    cvtw_k<<<2048, 256, 0, stream>>>(Wk, wqkv + 1048576, 1048576, 3145728, 1048576);
    cvtw_k<<<2048, 256, 0, stream>>>(Wv, wqkv + 2097152, 1048576, 3145728, 1048576);
    cvtw_k<<<2048, 256, 0, stream>>>(Wo, wob,            1048576, 1048576, 1048576);
    cvtw_k<<<2048, 256, 0, stream>>>(W1, w1b,            4194304, 4194304, 4194304);
    cvtw_k<<<2048, 256, 0, stream>>>(W2, w2b,            4194304, 4194304, 4194304);
  }
  xinit_k<<<2048, 256, 0, stream>>>(x, xf, xb, 524288);

  for (int lyr = 0; lyr < 4; ++lyr) {
    ebar_k<<<1024, 64, 0, stream>>>(rel + (size_t)lyr * 2047 * 64, ebar);

    if (preconv) {
      gemm_k<0><<<dim3(24, 16), 256, 0, stream>>>(xb, wqkv + (size_t)lyr * 3145728, 1024, 3072, 0,
          bq + lyr * 1024, bk + lyr * 1024, bv + lyr * 1024, ebar, qbp, kbp, vtp, nullptr, nullptr);
    } else {
      gemm_k<1><<<dim3(8, 16), 256, 0, stream>>>(xb, Wq + (size_t)lyr * 1048576, 1024, 1024, 1,
          bq + lyr * 1024, nullptr, nullptr, ebar, qbp, kbp, vtp, nullptr, nullptr);
      gemm_k<1><<<dim3(8, 16), 256, 0, stream>>>(xb, Wk + (size_t)lyr * 1048576, 1024, 1024, 2,
          bk + lyr * 1024, nullptr, nullptr, ebar, qbp, kbp, vtp, nullptr, nullptr);
      gemm_k<1><<<dim3(8, 16), 256, 0, stream>>>(xb, Wv + (size_t)lyr * 1048576, 1024, 1024, 3,
          bv + lyr * 1024, nullptr, nullptr, ebar, qbp, kbp, vtp, nullptr, nullptr);
    }

    attn_k<<<dim3(16, 32), 256, 0, stream>>>(qbp, kbp, vtp, ctx);

    if (preconv)
      gemm_k<0><<<dim3(8, 16), 256, 0, stream>>>(ctx, wob + (size_t)lyr * 1048576, 1024, 1024, 4,
          bo + lyr * 1024, nullptr, nullptr, nullptr, nullptr, nullptr, nullptr, yf, nullptr);
    else
      gemm_k<1><<<dim3(8, 16), 256, 0, stream>>>(ctx, Wo + (size_t)lyr * 1048576, 1024, 1024, 4,
          bo + lyr * 1024, nullptr, nullptr, nullptr, nullptr, nullptr, nullptr, yf, nullptr);

    ln_k<<<2048, 256, 0, stream>>>(xf, yf, g1 + lyr * 1024, be1 + lyr * 1024, xf, xb);

    if (preconv)
      gemm_k<0><<<dim3(32, 16), 256, 0, stream>>>(xb, w1b + (size_t)lyr * 4194304, 1024, 4096, 5,
          b1 + lyr * 4096, nullptr, nullptr, nullptr, nullptr, nullptr, nullptr, nullptr, hb);
    else
      gemm_k<1><<<dim3(32, 16), 256, 0, stream>>>(xb, W1 + (size_t)lyr * 4194304, 1024, 4096, 5,
          b1 + lyr * 4096, nullptr, nullptr, nullptr, nullptr, nullptr, nullptr, nullptr, hb);

    if (preconv)
      gemm_k<0><<<dim3(8, 16), 256, 0, stream>>>(hb, w2b + (size_t)lyr * 4194304, 4096, 1024, 4,
          b2 + lyr * 1024, nullptr, nullptr, nullptr, nullptr, nullptr, nullptr, yf, nullptr);
    else
      gemm_k<1><<<dim3(8, 16), 256, 0, stream>>>(hb, W2 + (size_t)lyr * 4194304, 4096, 1024, 4,
          b2 + lyr * 1024, nullptr, nullptr, nullptr, nullptr, nullptr, nullptr, yf, nullptr);

    ln_k<<<2048, 256, 0, stream>>>(xf, yf, g2 + lyr * 1024, be2 + lyr * 1024,
        (lyr == 3) ? out : xf, xb);
  }
}

// Round 2
// 1141.176 us; speedup vs baseline: 1.1525x; 1.1525x over previous
//
#include <hip/hip_runtime.h>
#include <math.h>

typedef __attribute__((ext_vector_type(4))) float f32x4;
typedef __attribute__((ext_vector_type(8))) short s16x8;
typedef __attribute__((ext_vector_type(8))) unsigned short u16x8;
typedef __attribute__((ext_vector_type(4))) unsigned short u16x4;

#define DI __device__ __forceinline__

DI unsigned short f2bf(float f) {
  unsigned int u = __builtin_bit_cast(unsigned int, f);
  u = u + 0x7fffu + ((u >> 16) & 1u);
  return (unsigned short)(u >> 16);
}

DI void gload16(const unsigned short* g, unsigned short* l) {
  __builtin_amdgcn_global_load_lds(
      (const __attribute__((address_space(1))) void*)g,
      (__attribute__((address_space(3))) void*)l, 16, 0, 0);
}

// ---------------- weight fp32 -> bf16 (chunk/stride packing) ----------------
__global__ __launch_bounds__(256) void cvtw_k(const float* __restrict__ src,
    unsigned short* __restrict__ dst, int chunk, int dstStride, int total4)
{
  for (int i = blockIdx.x * 256 + threadIdx.x; i < total4; i += gridDim.x * 256) {
    int idx = i * 4;
    int blk = idx / chunk, off = idx - blk * chunk;
    f32x4 v = *reinterpret_cast<const f32x4*>(src + idx);
    u16x4 o = { f2bf(v[0]), f2bf(v[1]), f2bf(v[2]), f2bf(v[3]) };
    *reinterpret_cast<u16x4*>(dst + (size_t)blk * dstStride + off) = o;
  }
}

// ---------------- x -> xf (f32 master) + xb (bf16 mirror) ----------------
__global__ __launch_bounds__(256) void xinit_k(const float* __restrict__ x,
    float* __restrict__ xf, unsigned short* __restrict__ xb, int n4)
{
  for (int i = blockIdx.x * 256 + threadIdx.x; i < n4; i += gridDim.x * 256) {
    f32x4 v = *reinterpret_cast<const f32x4*>(x + (size_t)i * 4);
    *reinterpret_cast<f32x4*>(xf + (size_t)i * 4) = v;
    u16x4 o = { f2bf(v[0]), f2bf(v[1]), f2bf(v[2]), f2bf(v[3]) };
    *reinterpret_cast<u16x4*>(xb + (size_t)i * 4) = o;
  }
}

// ---------------- Ebar[j,d] = mean over 1024-row sliding window ----------------
__global__ __launch_bounds__(256) void ebar_k(const float* __restrict__ rel,
    float* __restrict__ ebar)
{
  __shared__ float red[4][64];
  int j = blockIdx.x, d = threadIdx.x & 63, sg = threadIdx.x >> 6;
  const float* p = rel + (size_t)(1023 - j + sg * 256) * 64 + d;
  float s = 0.f;
  for (int k = 0; k < 256; ++k) s += p[(size_t)k * 64];
  red[sg][d] = s;
  __syncthreads();
  if (sg == 0)
    ebar[j * 64 + d] = (red[0][d] + red[1][d] + red[2][d] + red[3][d]) * (1.f / 1024.f);
}

// ---------------- GEMM: C[m,n] = sum_k A[m,k]*B[n,k] + bias, fused epilogues ----
// BF32=0: B bf16 (global_load_lds staging); BF32=1: B fp32 (reg-staged convert).
// mode 0: fused QKV (per-block qtype from n0); 1/2/3: Q/K'/V only (fallback)
// mode 4: fp32 partials -> yf[z] (O-proj, FFN2; split-K via blockIdx.z)
// mode 5: gelu bf16 -> hb (FFN1)
template<int BF32, int BN>
__global__ __launch_bounds__(256) void gemm_k(
    const unsigned short* __restrict__ A, const void* __restrict__ Bp,
    int K, int N, int mode, int kLen,
    const float* __restrict__ bias0, const float* __restrict__ bias1,
    const float* __restrict__ bias2, const float* __restrict__ ebar,
    unsigned short* __restrict__ qb, unsigned short* __restrict__ kb,
    unsigned short* __restrict__ vtb, float* __restrict__ yf,
    unsigned short* __restrict__ hb)
{
  constexpr int NI = BN / 32;            // per-wave n fragments
  constexpr int WC = BN / 2;             // per-wave col span
  constexpr int SMSZ = (128 + BN) * 64 > 128 * (BN + 8) ? (128 + BN) * 64 : 128 * (BN + 8);
  __shared__ __align__(16) unsigned short SM[SMSZ];
  auto As = reinterpret_cast<unsigned short(*)[64]>(SM);
  auto Bs = reinterpret_cast<unsigned short(*)[64]>(SM + 128 * 64);
  const int tid = threadIdx.x, l = tid & 63, w = tid >> 6;
  const int wr = w >> 1, wc = w & 1, lr = l & 15, lg = l >> 4;
  const int m0 = blockIdx.y * 128, n0 = blockIdx.x * BN;
  f32x4 acc[4][NI];
#pragma unroll
  for (int i = 0; i < 4; ++i)
#pragma unroll
    for (int j = 0; j < NI; ++j) acc[i][j] = f32x4{0.f, 0.f, 0.f, 0.f};

  const int kBeg = blockIdx.z * kLen, kEnd = kBeg + kLen;
  const unsigned short* gaBase = A + (size_t)(m0 + (l >> 3)) * K + (l & 7) * 8;

  for (int k0 = kBeg; k0 < kEnd; k0 += 64) {
    __syncthreads();
#pragma unroll
    for (int it = 0; it < 4; ++it) {
      int r0 = (w * 4 + it) * 8;
      gload16(gaBase + (size_t)r0 * K + k0, &As[r0][0]);
    }
    if (BF32 == 0) {
      const unsigned short* Bb = (const unsigned short*)Bp;
      const unsigned short* gb = Bb + (size_t)(n0 + (l >> 3)) * K + k0 + (l & 7) * 8;
#pragma unroll
      for (int it = 0; it < BN / 32; ++it) {
        int r0 = (w * (BN / 32) + it) * 8;
        gload16(gb + (size_t)r0 * K, &Bs[r0][0]);
      }
    } else {
      const float* Bf = (const float*)Bp;
#pragma unroll
      for (int it = 0; it < BN / 16; ++it) {
        int lin = (it * 256 + tid) * 4, r = lin >> 6, c = lin & 63;
        f32x4 v = *reinterpret_cast<const f32x4*>(Bf + (size_t)(n0 + r) * K + k0 + c);
        u16x4 o = { f2bf(v[0]), f2bf(v[1]), f2bf(v[2]), f2bf(v[3]) };
        *reinterpret_cast<u16x4*>(&Bs[r][c]) = o;
      }
    }
    __syncthreads();
#pragma unroll
    for (int kk = 0; kk < 2; ++kk) {
      s16x8 af[4], bfr[NI];
#pragma unroll
      for (int mi = 0; mi < 4; ++mi)
        af[mi] = *reinterpret_cast<const s16x8*>(&As[wr * 64 + mi * 16 + lr][kk * 32 + lg * 8]);
#pragma unroll
      for (int ni = 0; ni < NI; ++ni)
        bfr[ni] = *reinterpret_cast<const s16x8*>(&Bs[wc * WC + ni * 16 + lr][kk * 32 + lg * 8]);
#pragma unroll
      for (int mi = 0; mi < 4; ++mi)
#pragma unroll
        for (int ni = 0; ni < NI; ++ni)
          acc[mi][ni] = __builtin_amdgcn_mfma_f32_16x16x32_bf16(af[mi], bfr[ni], acc[mi][ni], 0, 0, 0);
    }
  }

  if (mode <= 3) {
    int qtype, nbase;
    const float* bias;
    if (mode == 0) {
      qtype = n0 >> 10; nbase = n0 & 1023;
      bias = qtype == 0 ? bias0 : (qtype == 1 ? bias1 : bias2);
    } else { qtype = mode - 1; nbase = n0; bias = bias0; }
    if (qtype < 2) {
      unsigned short* dst = (qtype == 0) ? qb : kb;
#pragma unroll
      for (int mi = 0; mi < 4; ++mi)
#pragma unroll
        for (int ni = 0; ni < NI; ++ni) {
          int nin = nbase + wc * WC + ni * 16 + lr;
          int hh = nin >> 6, dh = nin & 63;
          float bv = bias[nin];
#pragma unroll
          for (int rr = 0; rr < 4; ++rr) {
            int m = m0 + wr * 64 + mi * 16 + lg * 4 + rr;
            int b = m >> 10, s = m & 1023;
            float v = acc[mi][ni][rr] + bv;
            if (qtype == 1) v = v * 0.125f + ebar[s * 64 + dh];
            dst[(size_t)(b * 16 + hh) * 65536 + (size_t)s * 64 + dh] = f2bf(v);
          }
        }
    } else {
      // V: transpose-bounce through LDS, write vtb[B,H,HD,S] coalesced
      auto T = reinterpret_cast<unsigned short(*)[BN + 8]>(SM);
      __syncthreads();
#pragma unroll
      for (int mi = 0; mi < 4; ++mi)
#pragma unroll
        for (int ni = 0; ni < NI; ++ni) {
          int nl = wc * WC + ni * 16 + lr;
          float bv = bias[nbase + nl];
#pragma unroll
          for (int rr = 0; rr < 4; ++rr) {
            int ml = wr * 64 + mi * 16 + lg * 4 + rr;
            T[ml][nl] = f2bf(acc[mi][ni][rr] + bv);
          }
        }
      __syncthreads();
      int b = m0 >> 10, j0 = m0 & 1023;
#pragma unroll
      for (int lp = 0; lp < BN / 16; ++lp) {
        int dl = lp * 16 + (tid >> 4), jc = (tid & 15) * 8;
        u16x8 o;
#pragma unroll
        for (int e = 0; e < 8; ++e) o[e] = T[jc + e][dl];
        int nin = nbase + dl, hh = nin >> 6, dh = nin & 63;
        *reinterpret_cast<u16x8*>(vtb + (size_t)(b * 16 + hh) * 65536 + (size_t)dh * 1024 + j0 + jc) = o;
      }
    }
  } else {
    float* yfp = yf + (size_t)blockIdx.z * 2097152;
#pragma unroll
    for (int mi = 0; mi < 4; ++mi)
#pragma unroll
      for (int ni = 0; ni < NI; ++ni) {
        int nn = n0 + wc * WC + ni * 16 + lr;
        float bv = (blockIdx.z == 0) ? bias0[nn] : 0.f;
#pragma unroll
        for (int rr = 0; rr < 4; ++rr) {
          int m = m0 + wr * 64 + mi * 16 + lg * 4 + rr;
          float v = acc[mi][ni][rr] + bv;
          if (mode == 4) yfp[(size_t)m * N + nn] = v;
          else hb[(size_t)m * N + nn] = f2bf(0.5f * v * (1.f + erff(v * 0.70710678118654752f)));
        }
      }
  }
}

// ---------------- flash attention: softmax(Q K'^T) V, barrier-free ----------------
__global__ __launch_bounds__(256) void attn_k(const unsigned short* __restrict__ qb,
    const unsigned short* __restrict__ kb, const unsigned short* __restrict__ vtb,
    unsigned short* __restrict__ ctx)
{
  __shared__ __align__(16) unsigned short Pl[4][16][72];
  const int tq = blockIdx.x, bh = blockIdx.y;
  const int tid = threadIdx.x, l = tid & 63, w = tid >> 6;
  const int lr = l & 15, lg = l >> 4;
  const unsigned short* Kbase = kb + (size_t)bh * 65536;
  const unsigned short* Vbase = vtb + (size_t)bh * 65536;

  const unsigned short* Qp = qb + (size_t)bh * 65536 + (size_t)(tq * 64 + w * 16 + lr) * 64 + lg * 8;
  s16x8 qf[2];
  qf[0] = *reinterpret_cast<const s16x8*>(Qp);
  qf[1] = *reinterpret_cast<const s16x8*>(Qp + 32);

  f32x4 oacc[4];
#pragma unroll
  for (int di = 0; di < 4; ++di) oacc[di] = f32x4{0.f, 0.f, 0.f, 0.f};
  float M[4] = { -1e30f, -1e30f, -1e30f, -1e30f };
  float L[4] = { 0.f, 0.f, 0.f, 0.f };

  for (int jt = 0; jt < 16; ++jt) {
    f32x4 sacc[4];
#pragma unroll
    for (int ni = 0; ni < 4; ++ni) sacc[ni] = f32x4{0.f, 0.f, 0.f, 0.f};
#pragma unroll
    for (int kk = 0; kk < 2; ++kk) {
#pragma unroll
      for (int ni = 0; ni < 4; ++ni) {
        s16x8 kf = *reinterpret_cast<const s16x8*>(
            Kbase + (size_t)(jt * 64 + ni * 16 + lr) * 64 + kk * 32 + lg * 8);
        sacc[ni] = __builtin_amdgcn_mfma_f32_16x16x32_bf16(qf[kk], kf, sacc[ni], 0, 0, 0);
      }
    }
#pragma unroll
    for (int r = 0; r < 4; ++r) {
      float pm = fmaxf(fmaxf(sacc[0][r], sacc[1][r]), fmaxf(sacc[2][r], sacc[3][r]));
#pragma unroll
      for (int xm = 1; xm < 16; xm <<= 1) pm = fmaxf(pm, __shfl_xor(pm, xm));
      float mn = fmaxf(M[r], pm);
      float sc = expf(M[r] - mn);
      float rs = 0.f;
#pragma unroll
      for (int ni = 0; ni < 4; ++ni) { float p = expf(sacc[ni][r] - mn); sacc[ni][r] = p; rs += p; }
#pragma unroll
      for (int xm = 1; xm < 16; xm <<= 1) rs += __shfl_xor(rs, xm);
      M[r] = mn; L[r] = L[r] * sc + rs;
#pragma unroll
      for (int di = 0; di < 4; ++di) oacc[di][r] *= sc;
#pragma unroll
      for (int ni = 0; ni < 4; ++ni) Pl[w][lg * 4 + r][ni * 16 + lr] = f2bf(sacc[ni][r]);
    }
#pragma unroll
    for (int kk = 0; kk < 2; ++kk) {
      s16x8 pa = *reinterpret_cast<const s16x8*>(&Pl[w][lr][kk * 32 + lg * 8]);
#pragma unroll
      for (int di = 0; di < 4; ++di) {
        s16x8 vf = *reinterpret_cast<const s16x8*>(
            Vbase + (size_t)(di * 16 + lr) * 1024 + jt * 64 + kk * 32 + lg * 8);
        oacc[di] = __builtin_amdgcn_mfma_f32_16x16x32_bf16(pa, vf, oacc[di], 0, 0, 0);
      }
    }
  }
  const int b = bh >> 4, hh = bh & 15;
#pragma unroll
  for (int r = 0; r < 4; ++r) {
    float inv = 1.f / L[r];
    int qrow = tq * 64 + w * 16 + lg * 4 + r;
#pragma unroll
    for (int di = 0; di < 4; ++di)
      ctx[(size_t)(b * 1024 + qrow) * 1024 + hh * 64 + di * 16 + lr] = f2bf(oacc[di][r] * inv);
  }
}

// ---------------- LayerNorm(xf + yf0 + yf1) -> outf (f32) + outb (bf16) ----------------
__global__ __launch_bounds__(256) void ln_k(const float* __restrict__ xf,
    const float* __restrict__ yf, const float* __restrict__ g,
    const float* __restrict__ be, float* __restrict__ outf,
    unsigned short* __restrict__ outb)
{
  int row = blockIdx.x, tid = threadIdx.x, l = tid & 63, w = tid >> 6;
  size_t base = (size_t)row * 1024 + tid * 4;
  f32x4 v = *reinterpret_cast<const f32x4*>(xf + base);
  f32x4 y0 = *reinterpret_cast<const f32x4*>(yf + base);
  f32x4 y1 = *reinterpret_cast<const f32x4*>(yf + 2097152 + base);
  v = v + y0 + y1;
  float s = v[0] + v[1] + v[2] + v[3];
  float q = v[0] * v[0] + v[1] * v[1] + v[2] * v[2] + v[3] * v[3];
#pragma unroll
  for (int off = 1; off < 64; off <<= 1) { s += __shfl_xor(s, off); q += __shfl_xor(q, off); }
  __shared__ float ss[4], qq[4];
  if (l == 0) { ss[w] = s; qq[w] = q; }
  __syncthreads();
  s = ss[0] + ss[1] + ss[2] + ss[3];
  q = qq[0] + qq[1] + qq[2] + qq[3];
  float m = s * (1.f / 1024.f);
  float var = q * (1.f / 1024.f) - m * m;
  float rs = rsqrtf(var + 1e-5f);
  f32x4 gv = *reinterpret_cast<const f32x4*>(g + tid * 4);
  f32x4 bv = *reinterpret_cast<const f32x4*>(be + tid * 4);
  f32x4 o; u16x4 ob;
#pragma unroll
  for (int e = 0; e < 4; ++e) { o[e] = (v[e] - m) * rs * gv[e] + bv[e]; ob[e] = f2bf(o[e]); }
  *reinterpret_cast<f32x4*>(outf + base) = o;
  *reinterpret_cast<u16x4*>(outb + base) = ob;
}

// ---------------- host ----------------
extern "C" void kernel_launch(void* const* d_in, const int* in_sizes, int n_in,
                              void* d_out, int out_size, void* d_ws, size_t ws_size,
                              hipStream_t stream)
{
  (void)in_sizes; (void)n_in; (void)out_size;
  const float* x   = (const float*)d_in[0];
  const float* Wq  = (const float*)d_in[1];
  const float* bq  = (const float*)d_in[2];
  const float* Wk  = (const float*)d_in[3];
  const float* bk  = (const float*)d_in[4];
  const float* Wv  = (const float*)d_in[5];
  const float* bv  = (const float*)d_in[6];
  const float* Wo  = (const float*)d_in[7];
  const float* bo  = (const float*)d_in[8];
  const float* rel = (const float*)d_in[9];
  const float* W1  = (const float*)d_in[10];
  const float* b1  = (const float*)d_in[11];
  const float* W2  = (const float*)d_in[12];
  const float* b2  = (const float*)d_in[13];
  const float* g1  = (const float*)d_in[14];
  const float* be1 = (const float*)d_in[15];
  const float* g2  = (const float*)d_in[16];
  const float* be2 = (const float*)d_in[17];
  float* out = (float*)d_out;
  char* ws = (char*)d_ws;

  // activations
  const size_t OFF_XF = 0, OFF_YF = 8388608, OFF_XB = 25165824, OFF_QB = 29360128,
      OFF_KB = 33554432, OFF_VT = 37748736, OFF_CT = 41943040, OFF_HB = 46137344,
      OFF_EB = 62914560, OFF_W = 63176704;
  const size_t NEED_A = 163840000, NEED_B = 88342528;

  float* xf = (float*)(ws + OFF_XF);
  float* yf = (float*)(ws + OFF_YF);                 // 2 x 8MB split-K partials
  unsigned short* xb  = (unsigned short*)(ws + OFF_XB);
  unsigned short* qbp = (unsigned short*)(ws + OFF_QB);
  unsigned short* kbp = (unsigned short*)(ws + OFF_KB);
  unsigned short* vtp = (unsigned short*)(ws + OFF_VT);
  unsigned short* ctx = (unsigned short*)(ws + OFF_CT);
  unsigned short* hb  = (unsigned short*)(ws + OFF_HB);
  float* ebar = (float*)(ws + OFF_EB);
  unsigned short* wb = (unsigned short*)(ws + OFF_W);

  const int tier = (ws_size >= NEED_A) ? 0 : (ws_size >= NEED_B ? 1 : 2);

  if (tier == 0) {
    // full preconv, layer-strided packing
    cvtw_k<<<2048, 256, 0, stream>>>(Wq, wb,           1048576, 3145728, 1048576);
    cvtw_k<<<2048, 256, 0, stream>>>(Wk, wb + 1048576, 1048576, 3145728, 1048576);
    cvtw_k<<<2048, 256, 0, stream>>>(Wv, wb + 2097152, 1048576, 3145728, 1048576);
    cvtw_k<<<2048, 256, 0, stream>>>(Wo, wb + 12582912, 1048576, 1048576, 1048576);
    cvtw_k<<<2048, 256, 0, stream>>>(W1, wb + 16777216, 4194304, 4194304, 4194304);
    cvtw_k<<<2048, 256, 0, stream>>>(W2, wb + 33554432, 4194304, 4194304, 4194304);
  }
  xinit_k<<<2048, 256, 0, stream>>>(x, xf, xb, 524288);

  for (int lyr = 0; lyr < 4; ++lyr) {
    ebar_k<<<1024, 256, 0, stream>>>(rel + (size_t)lyr * 2047 * 64, ebar);

    const unsigned short *wqkvP, *woP, *w1P, *w2P;
    if (tier == 0) {
      wqkvP = wb + (size_t)lyr * 3145728;
      woP   = wb + 12582912 + (size_t)lyr * 1048576;
      w1P   = wb + 16777216 + (size_t)lyr * 4194304;
      w2P   = wb + 33554432 + (size_t)lyr * 4194304;
    } else if (tier == 1) {
      // per-layer conversion into 24MB rotating buffer
      wqkvP = wb; woP = wb + 3145728; w1P = wb + 4194304; w2P = wb + 8388608;
      cvtw_k<<<1024, 256, 0, stream>>>(Wq + (size_t)lyr * 1048576, wb,           1 << 30, 0, 262144);
      cvtw_k<<<1024, 256, 0, stream>>>(Wk + (size_t)lyr * 1048576, wb + 1048576, 1 << 30, 0, 262144);
      cvtw_k<<<1024, 256, 0, stream>>>(Wv + (size_t)lyr * 1048576, wb + 2097152, 1 << 30, 0, 262144);
      cvtw_k<<<1024, 256, 0, stream>>>(Wo + (size_t)lyr * 1048576, wb + 3145728, 1 << 30, 0, 262144);
      cvtw_k<<<2048, 256, 0, stream>>>(W1 + (size_t)lyr * 4194304, wb + 4194304, 1 << 30, 0, 1048576);
      cvtw_k<<<2048, 256, 0, stream>>>(W2 + (size_t)lyr * 4194304, wb + 8388608, 1 << 30, 0, 1048576);
    } else { wqkvP = woP = w1P = w2P = nullptr; }

    if (tier <= 1) {
      gemm_k<0, 64><<<dim3(48, 16), 256, 0, stream>>>(xb, wqkvP, 1024, 3072, 0, 1024,
          bq + lyr * 1024, bk + lyr * 1024, bv + lyr * 1024, ebar, qbp, kbp, vtp, nullptr, nullptr);
    } else {
      gemm_k<1, 128><<<dim3(8, 16), 256, 0, stream>>>(xb, Wq + (size_t)lyr * 1048576, 1024, 1024, 1, 1024,
          bq + lyr * 1024, nullptr, nullptr, ebar, qbp, kbp, vtp, nullptr, nullptr);
      gemm_k<1, 128><<<dim3(8, 16), 256, 0, stream>>>(xb, Wk + (size_t)lyr * 1048576, 1024, 1024, 2, 1024,
          bk + lyr * 1024, nullptr, nullptr, ebar, qbp, kbp, vtp, nullptr, nullptr);
      gemm_k<1, 128><<<dim3(8, 16), 256, 0, stream>>>(xb, Wv + (size_t)lyr * 1048576, 1024, 1024, 3, 1024,
          bv + lyr * 1024, nullptr, nullptr, ebar, qbp, kbp, vtp, nullptr, nullptr);
    }

    attn_k<<<dim3(16, 32), 256, 0, stream>>>(qbp, kbp, vtp, ctx);

    if (tier <= 1)
      gemm_k<0, 64><<<dim3(16, 16, 2), 256, 0, stream>>>(ctx, woP, 1024, 1024, 4, 512,
          bo + lyr * 1024, nullptr, nullptr, nullptr, nullptr, nullptr, nullptr, yf, nullptr);
    else
      gemm_k<1, 64><<<dim3(16, 16, 2), 256, 0, stream>>>(ctx, Wo + (size_t)lyr * 1048576, 1024, 1024, 4, 512,
          bo + lyr * 1024, nullptr, nullptr, nullptr, nullptr, nullptr, nullptr, yf, nullptr);

    ln_k<<<2048, 256, 0, stream>>>(xf, yf, g1 + lyr * 1024, be1 + lyr * 1024, xf, xb);

    if (tier <= 1)
      gemm_k<0, 128><<<dim3(32, 16), 256, 0, stream>>>(xb, w1P, 1024, 4096, 5, 1024,
          b1 + lyr * 4096, nullptr, nullptr, nullptr, nullptr, nullptr, nullptr, nullptr, hb);
    else
      gemm_k<1, 128><<<dim3(32, 16), 256, 0, stream>>>(xb, W1 + (size_t)lyr * 4194304, 1024, 4096, 5, 1024,
          b1 + lyr * 4096, nullptr, nullptr, nullptr, nullptr, nullptr, nullptr, nullptr, hb);

    if (tier <= 1)
      gemm_k<0, 64><<<dim3(16, 16, 2), 256, 0, stream>>>(hb, w2P, 4096, 1024, 4, 2048,
          b2 + lyr * 1024, nullptr, nullptr, nullptr, nullptr, nullptr, nullptr, yf, nullptr);
    else
      gemm_k<1, 64><<<dim3(16, 16, 2), 256, 0, stream>>>(hb, W2 + (size_t)lyr * 4194304, 4096, 1024, 4, 2048,
          b2 + lyr * 1024, nullptr, nullptr, nullptr, nullptr, nullptr, nullptr, yf, nullptr);

    ln_k<<<2048, 256, 0, stream>>>(xf, yf, g2 + lyr * 1024, be2 + lyr * 1024,
        (lyr == 3) ? out : xf, xb);
  }
}

// Round 3
// 960.260 us; speedup vs baseline: 1.3696x; 1.1884x over previous
//
#include <hip/hip_runtime.h>
#include <math.h>

typedef __attribute__((ext_vector_type(4))) float f32x4;
typedef __attribute__((ext_vector_type(8))) short s16x8;
typedef __attribute__((ext_vector_type(8))) unsigned short u16x8;
typedef __attribute__((ext_vector_type(4))) unsigned short u16x4;

#define DI __device__ __forceinline__

DI unsigned short f2bf(float f) {
  unsigned int u = __builtin_bit_cast(unsigned int, f);
  u = u + 0x7fffu + ((u >> 16) & 1u);
  return (unsigned short)(u >> 16);
}

DI void gload16(const unsigned short* g, unsigned short* l) {
  __builtin_amdgcn_global_load_lds(
      (const __attribute__((address_space(1))) void*)g,
      (__attribute__((address_space(3))) void*)l, 16, 0, 0);
}

// ---------------- weight fp32 -> bf16 (chunk/stride packing) ----------------
__global__ __launch_bounds__(256) void cvtw_k(const float* __restrict__ src,
    unsigned short* __restrict__ dst, int chunk, int dstStride, int total4)
{
  for (int i = blockIdx.x * 256 + threadIdx.x; i < total4; i += gridDim.x * 256) {
    int idx = i * 4;
    int blk = idx / chunk, off = idx - blk * chunk;
    f32x4 v = *reinterpret_cast<const f32x4*>(src + idx);
    u16x4 o = { f2bf(v[0]), f2bf(v[1]), f2bf(v[2]), f2bf(v[3]) };
    *reinterpret_cast<u16x4*>(dst + (size_t)blk * dstStride + off) = o;
  }
}

// ---------------- x -> xf (f32 master) + xb (bf16 mirror) ----------------
__global__ __launch_bounds__(256) void xinit_k(const float* __restrict__ x,
    float* __restrict__ xf, unsigned short* __restrict__ xb, int n4)
{
  for (int i = blockIdx.x * 256 + threadIdx.x; i < n4; i += gridDim.x * 256) {
    f32x4 v = *reinterpret_cast<const f32x4*>(x + (size_t)i * 4);
    *reinterpret_cast<f32x4*>(xf + (size_t)i * 4) = v;
    u16x4 o = { f2bf(v[0]), f2bf(v[1]), f2bf(v[2]), f2bf(v[3]) };
    *reinterpret_cast<u16x4*>(xb + (size_t)i * 4) = o;
  }
}

// ---------------- Ebar precompute: chunk sums then windowed sums ----------------
__global__ __launch_bounds__(64) void ebch_k(const float* __restrict__ rel,
    float* __restrict__ cs)
{
  int c = blockIdx.x, L = blockIdx.y, d = threadIdx.x;
  const float* p = rel + ((size_t)L * 2047 + c * 64) * 64 + d;
  int n = (c == 31) ? 63 : 64;
  float s = 0.f;
  for (int k = 0; k < n; ++k) s += p[(size_t)k * 64];
  cs[(L * 32 + c) * 64 + d] = s;
}

__global__ __launch_bounds__(64) void ebar_k(const float* __restrict__ rel,
    const float* __restrict__ cs, float* __restrict__ ebar4)
{
  int j = blockIdx.x, L = blockIdx.y, d = threadIdx.x;
  int s = 1023 - j, e = s + 1024;
  int c0 = (s + 63) >> 6, c1 = e >> 6;
  const float* rl = rel + (size_t)L * 2047 * 64;
  const float* cl = cs + L * 32 * 64;
  float acc = 0.f;
  for (int c = c0; c < c1; ++c) acc += cl[c * 64 + d];
  for (int t = s; t < c0 * 64; ++t) acc += rl[(size_t)t * 64 + d];
  for (int t = c1 * 64; t < e; ++t) acc += rl[(size_t)t * 64 + d];
  ebar4[((size_t)L * 1024 + j) * 64 + d] = acc * (1.f / 1024.f);
}

// ---------------- GEMM: C[m,n] = sum_k A[m,k]*B[n,k] + bias, fused epilogues ----
template<int BF32, int BN>
__global__ __launch_bounds__(256) void gemm_k(
    const unsigned short* __restrict__ A, const void* __restrict__ Bp,
    int K, int N, int mode, int kLen,
    const float* __restrict__ bias0, const float* __restrict__ bias1,
    const float* __restrict__ bias2, const float* __restrict__ ebar,
    unsigned short* __restrict__ qb, unsigned short* __restrict__ kb,
    unsigned short* __restrict__ vtb, float* __restrict__ yf,
    unsigned short* __restrict__ hb)
{
  constexpr int NI = BN / 32;
  constexpr int WC = BN / 2;
  constexpr int SMSZ = (128 + BN) * 64 > 128 * (BN + 8) ? (128 + BN) * 64 : 128 * (BN + 8);
  __shared__ __align__(16) unsigned short SM[SMSZ];
  auto As = reinterpret_cast<unsigned short(*)[64]>(SM);
  auto Bs = reinterpret_cast<unsigned short(*)[64]>(SM + 128 * 64);
  const int tid = threadIdx.x, l = tid & 63, w = tid >> 6;
  const int wr = w >> 1, wc = w & 1, lr = l & 15, lg = l >> 4;
  const int m0 = blockIdx.y * 128, n0 = blockIdx.x * BN;
  f32x4 acc[4][NI];
#pragma unroll
  for (int i = 0; i < 4; ++i)
#pragma unroll
    for (int j = 0; j < NI; ++j) acc[i][j] = f32x4{0.f, 0.f, 0.f, 0.f};

  const int kBeg = blockIdx.z * kLen, kEnd = kBeg + kLen;
  const unsigned short* gaBase = A + (size_t)(m0 + (l >> 3)) * K + (l & 7) * 8;

  for (int k0 = kBeg; k0 < kEnd; k0 += 64) {
    __syncthreads();
#pragma unroll
    for (int it = 0; it < 4; ++it) {
      int r0 = (w * 4 + it) * 8;
      gload16(gaBase + (size_t)r0 * K + k0, &As[r0][0]);
    }
    if (BF32 == 0) {
      const unsigned short* Bb = (const unsigned short*)Bp;
      const unsigned short* gb = Bb + (size_t)(n0 + (l >> 3)) * K + k0 + (l & 7) * 8;
#pragma unroll
      for (int it = 0; it < BN / 32; ++it) {
        int r0 = (w * (BN / 32) + it) * 8;
        gload16(gb + (size_t)r0 * K, &Bs[r0][0]);
      }
    } else {
      const float* Bf = (const float*)Bp;
#pragma unroll
      for (int it = 0; it < BN / 16; ++it) {
        int lin = (it * 256 + tid) * 4, r = lin >> 6, c = lin & 63;
        f32x4 v = *reinterpret_cast<const f32x4*>(Bf + (size_t)(n0 + r) * K + k0 + c);
        u16x4 o = { f2bf(v[0]), f2bf(v[1]), f2bf(v[2]), f2bf(v[3]) };
        *reinterpret_cast<u16x4*>(&Bs[r][c]) = o;
      }
    }
    __syncthreads();
#pragma unroll
    for (int kk = 0; kk < 2; ++kk) {
      s16x8 af[4], bfr[NI];
#pragma unroll
      for (int mi = 0; mi < 4; ++mi)
        af[mi] = *reinterpret_cast<const s16x8*>(&As[wr * 64 + mi * 16 + lr][kk * 32 + lg * 8]);
#pragma unroll
      for (int ni = 0; ni < NI; ++ni)
        bfr[ni] = *reinterpret_cast<const s16x8*>(&Bs[wc * WC + ni * 16 + lr][kk * 32 + lg * 8]);
#pragma unroll
      for (int mi = 0; mi < 4; ++mi)
#pragma unroll
        for (int ni = 0; ni < NI; ++ni)
          acc[mi][ni] = __builtin_amdgcn_mfma_f32_16x16x32_bf16(af[mi], bfr[ni], acc[mi][ni], 0, 0, 0);
    }
  }

  if (mode <= 3) {
    int qtype, nbase;
    const float* bias;
    if (mode == 0) {
      qtype = n0 >> 10; nbase = n0 & 1023;
      bias = qtype == 0 ? bias0 : (qtype == 1 ? bias1 : bias2);
    } else { qtype = mode - 1; nbase = n0; bias = bias0; }
    if (qtype < 2) {
      unsigned short* dst = (qtype == 0) ? qb : kb;
#pragma unroll
      for (int mi = 0; mi < 4; ++mi)
#pragma unroll
        for (int ni = 0; ni < NI; ++ni) {
          int nin = nbase + wc * WC + ni * 16 + lr;
          int hh = nin >> 6, dh = nin & 63;
          float bv = bias[nin];
#pragma unroll
          for (int rr = 0; rr < 4; ++rr) {
            int m = m0 + wr * 64 + mi * 16 + lg * 4 + rr;
            int b = m >> 10, s = m & 1023;
            float v = acc[mi][ni][rr] + bv;
            if (qtype == 1) v = v * 0.125f + ebar[s * 64 + dh];
            dst[(size_t)(b * 16 + hh) * 65536 + (size_t)s * 64 + dh] = f2bf(v);
          }
        }
    } else {
      auto T = reinterpret_cast<unsigned short(*)[BN + 8]>(SM);
      __syncthreads();
#pragma unroll
      for (int mi = 0; mi < 4; ++mi)
#pragma unroll
        for (int ni = 0; ni < NI; ++ni) {
          int nl = wc * WC + ni * 16 + lr;
          float bv = bias[nbase + nl];
#pragma unroll
          for (int rr = 0; rr < 4; ++rr) {
            int ml = wr * 64 + mi * 16 + lg * 4 + rr;
            T[ml][nl] = f2bf(acc[mi][ni][rr] + bv);
          }
        }
      __syncthreads();
      int b = m0 >> 10, j0 = m0 & 1023;
#pragma unroll
      for (int lp = 0; lp < BN / 16; ++lp) {
        int dl = lp * 16 + (tid >> 4), jc = (tid & 15) * 8;
        u16x8 o;
#pragma unroll
        for (int e = 0; e < 8; ++e) o[e] = T[jc + e][dl];
        int nin = nbase + dl, hh = nin >> 6, dh = nin & 63;
        *reinterpret_cast<u16x8*>(vtb + (size_t)(b * 16 + hh) * 65536 + (size_t)dh * 1024 + j0 + jc) = o;
      }
    }
  } else {
    float* yfp = yf + (size_t)blockIdx.z * 2097152;
#pragma unroll
    for (int mi = 0; mi < 4; ++mi)
#pragma unroll
      for (int ni = 0; ni < NI; ++ni) {
        int nn = n0 + wc * WC + ni * 16 + lr;
        float bv = (blockIdx.z == 0) ? bias0[nn] : 0.f;
#pragma unroll
        for (int rr = 0; rr < 4; ++rr) {
          int m = m0 + wr * 64 + mi * 16 + lg * 4 + rr;
          float v = acc[mi][ni][rr] + bv;
          if (mode == 4) yfp[(size_t)m * N + nn] = v;
          else hb[(size_t)m * N + nn] = f2bf(0.5f * v * (1.f + erff(v * 0.70710678118654752f)));
        }
      }
  }
}

// ---------------- flash attention v3: LDS-staged, prefetch, no-max softmax,
//                  KV-split x2, XCD-bijective grid ----------------
__global__ __launch_bounds__(256, 4) void attn_k(const unsigned short* __restrict__ qb,
    const unsigned short* __restrict__ kb, const unsigned short* __restrict__ vtb,
    float* __restrict__ opart, float* __restrict__ lpart)
{
  __shared__ __align__(16) unsigned short Ks[2][64][72];
  __shared__ __align__(16) unsigned short Vs[64][72];
  __shared__ __align__(16) unsigned short Pl[4][16][72];
  const int id = blockIdx.x;
  const int xcd = id & 7, sub = id >> 3;
  const int bh = xcd * 4 + (sub >> 5);
  const int rest = sub & 31;
  const int tq = rest >> 1, half = rest & 1;
  const int tid = threadIdx.x, l = tid & 63, w = tid >> 6;
  const int lr = l & 15, lg = l >> 4;
  const int jt0 = half * 8;

  const unsigned short* Kb = kb + (size_t)bh * 65536;
  const unsigned short* Vb = vtb + (size_t)bh * 65536;

  const unsigned short* Qp = qb + (size_t)bh * 65536 +
      (size_t)(tq * 64 + w * 16 + lr) * 64 + lg * 8;
  s16x8 qf0 = *reinterpret_cast<const s16x8*>(Qp);
  s16x8 qf1 = *reinterpret_cast<const s16x8*>(Qp + 32);

  const int srow = tid >> 2, scol = (tid & 3) * 16;
  const unsigned short* kg = Kb + (size_t)srow * 64 + scol + (size_t)jt0 * 4096;
  const unsigned short* vg = Vb + (size_t)srow * 1024 + scol + (size_t)jt0 * 64;

  u16x8 krg[2][2], vrg[2][2];
  f32x4 oacc[4];
#pragma unroll
  for (int di = 0; di < 4; ++di) oacc[di] = f32x4{0.f, 0.f, 0.f, 0.f};
  float Lp[4] = { 0.f, 0.f, 0.f, 0.f };

  // prologue: tile 0 -> regs -> LDS buf0; prefetch tile 1 into set 1
  krg[0][0] = *reinterpret_cast<const u16x8*>(kg);
  krg[0][1] = *reinterpret_cast<const u16x8*>(kg + 8);
  vrg[0][0] = *reinterpret_cast<const u16x8*>(vg);
  vrg[0][1] = *reinterpret_cast<const u16x8*>(vg + 8);
  *reinterpret_cast<u16x8*>(&Ks[0][srow][scol]) = krg[0][0];
  *reinterpret_cast<u16x8*>(&Ks[0][srow][scol + 8]) = krg[0][1];
  krg[1][0] = *reinterpret_cast<const u16x8*>(kg + 4096);
  krg[1][1] = *reinterpret_cast<const u16x8*>(kg + 4096 + 8);
  vrg[1][0] = *reinterpret_cast<const u16x8*>(vg + 64);
  vrg[1][1] = *reinterpret_cast<const u16x8*>(vg + 64 + 8);

#pragma unroll
  for (int it = 0; it < 8; ++it) {
    const int buf = it & 1, nxt = buf ^ 1;
    asm volatile("s_waitcnt lgkmcnt(0)" ::: "memory");
    __builtin_amdgcn_s_barrier();
    __builtin_amdgcn_sched_barrier(0);
    // V tile `it` into Vs (regs loaded >=1 iter ago)
    *reinterpret_cast<u16x8*>(&Vs[srow][scol]) = vrg[buf][0];
    *reinterpret_cast<u16x8*>(&Vs[srow][scol + 8]) = vrg[buf][1];
    // QK from Ks[buf]
    f32x4 sacc[4];
#pragma unroll
    for (int ni = 0; ni < 4; ++ni) sacc[ni] = f32x4{0.f, 0.f, 0.f, 0.f};
#pragma unroll
    for (int kk = 0; kk < 2; ++kk) {
      s16x8 qq = kk ? qf1 : qf0;
#pragma unroll
      for (int ni = 0; ni < 4; ++ni) {
        s16x8 kf = *reinterpret_cast<const s16x8*>(&Ks[buf][ni * 16 + lr][kk * 32 + lg * 8]);
        sacc[ni] = __builtin_amdgcn_mfma_f32_16x16x32_bf16(qq, kf, sacc[ni], 0, 0, 0);
      }
    }
    // no-max softmax: P = exp(min(S,80)), defer L reduction
#pragma unroll
    for (int r = 0; r < 4; ++r) {
#pragma unroll
      for (int ni = 0; ni < 4; ++ni) {
        float p = __expf(fminf(sacc[ni][r], 80.f));
        Lp[r] += p;
        Pl[w][lg * 4 + r][ni * 16 + lr] = f2bf(p);
      }
    }
    asm volatile("s_waitcnt lgkmcnt(0)" ::: "memory");
    __builtin_amdgcn_s_barrier();
    __builtin_amdgcn_sched_barrier(0);
    // PV from Vs, Pl
#pragma unroll
    for (int kk = 0; kk < 2; ++kk) {
      s16x8 pa = *reinterpret_cast<const s16x8*>(&Pl[w][lr][kk * 32 + lg * 8]);
#pragma unroll
      for (int di = 0; di < 4; ++di) {
        s16x8 vf = *reinterpret_cast<const s16x8*>(&Vs[di * 16 + lr][kk * 32 + lg * 8]);
        oacc[di] = __builtin_amdgcn_mfma_f32_16x16x32_bf16(pa, vf, oacc[di], 0, 0, 0);
      }
    }
    // write K tile it+1 to Ks[nxt]; issue loads for tile it+2 into set `buf`
    if (it < 7) {
      *reinterpret_cast<u16x8*>(&Ks[nxt][srow][scol]) = krg[nxt][0];
      *reinterpret_cast<u16x8*>(&Ks[nxt][srow][scol + 8]) = krg[nxt][1];
    }
    if (it < 6) {
      const unsigned short* kp = kg + (size_t)(it + 2) * 4096;
      const unsigned short* vp = vg + (size_t)(it + 2) * 64;
      krg[buf][0] = *reinterpret_cast<const u16x8*>(kp);
      krg[buf][1] = *reinterpret_cast<const u16x8*>(kp + 8);
      vrg[buf][0] = *reinterpret_cast<const u16x8*>(vp);
      vrg[buf][1] = *reinterpret_cast<const u16x8*>(vp + 8);
    }
  }

  // L reduction across the 16-lane row group
#pragma unroll
  for (int r = 0; r < 4; ++r) {
#pragma unroll
    for (int xm = 1; xm < 16; xm <<= 1) Lp[r] += __shfl_xor(Lp[r], xm);
  }
  const size_t obase = ((size_t)(half * 32 + bh) * 1024 + tq * 64 + w * 16);
#pragma unroll
  for (int r = 0; r < 4; ++r) {
    int qrow = lg * 4 + r;
#pragma unroll
    for (int di = 0; di < 4; ++di)
      opart[(obase + qrow) * 64 + di * 16 + lr] = oacc[di][r];
    if (lr == 0) lpart[obase + qrow] = Lp[r];
  }
}

// ---------------- merge KV-split partials -> ctx (bf16) ----------------
__global__ __launch_bounds__(256) void amrg_k(const float* __restrict__ opart,
    const float* __restrict__ lpart, unsigned short* __restrict__ ctx)
{
  int e4 = blockIdx.x * 256 + threadIdx.x;
  int d4 = e4 & 15, q = (e4 >> 4) & 1023, bh = e4 >> 14;
  size_t po = ((size_t)bh * 1024 + q) * 64 + d4 * 4;
  f32x4 o0 = *reinterpret_cast<const f32x4*>(opart + po);
  f32x4 o1 = *reinterpret_cast<const f32x4*>(opart + 2097152 + po);
  float linv = 1.f / (lpart[bh * 1024 + q] + lpart[32768 + bh * 1024 + q]);
  int b = bh >> 4, h = bh & 15;
  u16x4 o;
#pragma unroll
  for (int e = 0; e < 4; ++e) o[e] = f2bf((o0[e] + o1[e]) * linv);
  *reinterpret_cast<u16x4*>(ctx + (size_t)(b * 1024 + q) * 1024 + h * 64 + d4 * 4) = o;
}

// ---------------- LayerNorm(xf + yf0 + yf1) -> outf (f32) + outb (bf16) ----------------
__global__ __launch_bounds__(256) void ln_k(const float* __restrict__ xf,
    const float* __restrict__ yf, const float* __restrict__ g,
    const float* __restrict__ be, float* __restrict__ outf,
    unsigned short* __restrict__ outb)
{
  int row = blockIdx.x, tid = threadIdx.x, l = tid & 63, w = tid >> 6;
  size_t base = (size_t)row * 1024 + tid * 4;
  f32x4 v = *reinterpret_cast<const f32x4*>(xf + base);
  f32x4 y0 = *reinterpret_cast<const f32x4*>(yf + base);
  f32x4 y1 = *reinterpret_cast<const f32x4*>(yf + 2097152 + base);
  v = v + y0 + y1;
  float s = v[0] + v[1] + v[2] + v[3];
  float q = v[0] * v[0] + v[1] * v[1] + v[2] * v[2] + v[3] * v[3];
#pragma unroll
  for (int off = 1; off < 64; off <<= 1) { s += __shfl_xor(s, off); q += __shfl_xor(q, off); }
  __shared__ float ss[4], qq[4];
  if (l == 0) { ss[w] = s; qq[w] = q; }
  __syncthreads();
  s = ss[0] + ss[1] + ss[2] + ss[3];
  q = qq[0] + qq[1] + qq[2] + qq[3];
  float m = s * (1.f / 1024.f);
  float var = q * (1.f / 1024.f) - m * m;
  float rs = rsqrtf(var + 1e-5f);
  f32x4 gv = *reinterpret_cast<const f32x4*>(g + tid * 4);
  f32x4 bv = *reinterpret_cast<const f32x4*>(be + tid * 4);
  f32x4 o; u16x4 ob;
#pragma unroll
  for (int e = 0; e < 4; ++e) { o[e] = (v[e] - m) * rs * gv[e] + bv[e]; ob[e] = f2bf(o[e]); }
  *reinterpret_cast<f32x4*>(outf + base) = o;
  *reinterpret_cast<u16x4*>(outb + base) = ob;
}

// ---------------- host ----------------
extern "C" void kernel_launch(void* const* d_in, const int* in_sizes, int n_in,
                              void* d_out, int out_size, void* d_ws, size_t ws_size,
                              hipStream_t stream)
{
  (void)in_sizes; (void)n_in; (void)out_size;
  const float* x   = (const float*)d_in[0];
  const float* Wq  = (const float*)d_in[1];
  const float* bq  = (const float*)d_in[2];
  const float* Wk  = (const float*)d_in[3];
  const float* bk  = (const float*)d_in[4];
  const float* Wv  = (const float*)d_in[5];
  const float* bv  = (const float*)d_in[6];
  const float* Wo  = (const float*)d_in[7];
  const float* bo  = (const float*)d_in[8];
  const float* rel = (const float*)d_in[9];
  const float* W1  = (const float*)d_in[10];
  const float* b1  = (const float*)d_in[11];
  const float* W2  = (const float*)d_in[12];
  const float* b2  = (const float*)d_in[13];
  const float* g1  = (const float*)d_in[14];
  const float* be1 = (const float*)d_in[15];
  const float* g2  = (const float*)d_in[16];
  const float* be2 = (const float*)d_in[17];
  float* out = (float*)d_out;
  char* ws = (char*)d_ws;

  const size_t OFF_XF = 0, OFF_YF = 8388608, OFF_XB = 25165824, OFF_QB = 29360128,
      OFF_KB = 33554432, OFF_VT = 37748736, OFF_CT = 41943040,
      OFF_HB = 46137344 /* hb 16MB, overlaid with opart */,
      OFF_LP = 62914560, OFF_EB = 63176704, OFF_CS = 64225280, OFF_W = 64258048;
  const size_t NEED_A = OFF_W + 100663296, NEED_B = OFF_W + 25165824;

  float* xf = (float*)(ws + OFF_XF);
  float* yf = (float*)(ws + OFF_YF);
  unsigned short* xb  = (unsigned short*)(ws + OFF_XB);
  unsigned short* qbp = (unsigned short*)(ws + OFF_QB);
  unsigned short* kbp = (unsigned short*)(ws + OFF_KB);
  unsigned short* vtp = (unsigned short*)(ws + OFF_VT);
  unsigned short* ctx = (unsigned short*)(ws + OFF_CT);
  unsigned short* hb  = (unsigned short*)(ws + OFF_HB);
  float* opart = (float*)(ws + OFF_HB);      // overlay: attn phase only
  float* lpart = (float*)(ws + OFF_LP);
  float* ebar4 = (float*)(ws + OFF_EB);
  float* csum  = (float*)(ws + OFF_CS);
  unsigned short* wb = (unsigned short*)(ws + OFF_W);

  const int tier = (ws_size >= NEED_A) ? 0 : (ws_size >= NEED_B ? 1 : 2);

  if (tier == 0) {
    cvtw_k<<<2048, 256, 0, stream>>>(Wq, wb,           1048576, 3145728, 1048576);
    cvtw_k<<<2048, 256, 0, stream>>>(Wk, wb + 1048576, 1048576, 3145728, 1048576);
    cvtw_k<<<2048, 256, 0, stream>>>(Wv, wb + 2097152, 1048576, 3145728, 1048576);
    cvtw_k<<<2048, 256, 0, stream>>>(Wo, wb + 12582912, 1048576, 1048576, 1048576);
    cvtw_k<<<2048, 256, 0, stream>>>(W1, wb + 16777216, 4194304, 4194304, 4194304);
    cvtw_k<<<2048, 256, 0, stream>>>(W2, wb + 33554432, 4194304, 4194304, 4194304);
  }
  xinit_k<<<2048, 256, 0, stream>>>(x, xf, xb, 524288);
  ebch_k<<<dim3(32, 4), 64, 0, stream>>>(rel, csum);
  ebar_k<<<dim3(1024, 4), 64, 0, stream>>>(rel, csum, ebar4);

  for (int lyr = 0; lyr < 4; ++lyr) {
    const float* eb = ebar4 + (size_t)lyr * 65536;
    const unsigned short *wqkvP, *woP, *w1P, *w2P;
    if (tier == 0) {
      wqkvP = wb + (size_t)lyr * 3145728;
      woP   = wb + 12582912 + (size_t)lyr * 1048576;
      w1P   = wb + 16777216 + (size_t)lyr * 4194304;
      w2P   = wb + 33554432 + (size_t)lyr * 4194304;
    } else if (tier == 1) {
      wqkvP = wb; woP = wb + 3145728; w1P = wb + 4194304; w2P = wb + 8388608;
      cvtw_k<<<1024, 256, 0, stream>>>(Wq + (size_t)lyr * 1048576, wb,           1 << 30, 0, 262144);
      cvtw_k<<<1024, 256, 0, stream>>>(Wk + (size_t)lyr * 1048576, wb + 1048576, 1 << 30, 0, 262144);
      cvtw_k<<<1024, 256, 0, stream>>>(Wv + (size_t)lyr * 1048576, wb + 2097152, 1 << 30, 0, 262144);
      cvtw_k<<<1024, 256, 0, stream>>>(Wo + (size_t)lyr * 1048576, wb + 3145728, 1 << 30, 0, 262144);
      cvtw_k<<<2048, 256, 0, stream>>>(W1 + (size_t)lyr * 4194304, wb + 4194304, 1 << 30, 0, 1048576);
      cvtw_k<<<2048, 256, 0, stream>>>(W2 + (size_t)lyr * 4194304, wb + 8388608, 1 << 30, 0, 1048576);
    } else { wqkvP = woP = w1P = w2P = nullptr; }

    if (tier <= 1) {
      gemm_k<0, 64><<<dim3(48, 16), 256, 0, stream>>>(xb, wqkvP, 1024, 3072, 0, 1024,
          bq + lyr * 1024, bk + lyr * 1024, bv + lyr * 1024, eb, qbp, kbp, vtp, nullptr, nullptr);
    } else {
      gemm_k<1, 128><<<dim3(8, 16), 256, 0, stream>>>(xb, Wq + (size_t)lyr * 1048576, 1024, 1024, 1, 1024,
          bq + lyr * 1024, nullptr, nullptr, eb, qbp, kbp, vtp, nullptr, nullptr);
      gemm_k<1, 128><<<dim3(8, 16), 256, 0, stream>>>(xb, Wk + (size_t)lyr * 1048576, 1024, 1024, 2, 1024,
          bk + lyr * 1024, nullptr, nullptr, eb, qbp, kbp, vtp, nullptr, nullptr);
      gemm_k<1, 128><<<dim3(8, 16), 256, 0, stream>>>(xb, Wv + (size_t)lyr * 1048576, 1024, 1024, 3, 1024,
          bv + lyr * 1024, nullptr, nullptr, eb, qbp, kbp, vtp, nullptr, nullptr);
    }

    attn_k<<<1024, 256, 0, stream>>>(qbp, kbp, vtp, opart, lpart);
    amrg_k<<<2048, 256, 0, stream>>>(opart, lpart, ctx);

    if (tier <= 1)
      gemm_k<0, 64><<<dim3(16, 16, 2), 256, 0, stream>>>(ctx, woP, 1024, 1024, 4, 512,
          bo + lyr * 1024, nullptr, nullptr, nullptr, nullptr, nullptr, nullptr, yf, nullptr);
    else
      gemm_k<1, 64><<<dim3(16, 16, 2), 256, 0, stream>>>(ctx, Wo + (size_t)lyr * 1048576, 1024, 1024, 4, 512,
          bo + lyr * 1024, nullptr, nullptr, nullptr, nullptr, nullptr, nullptr, yf, nullptr);

    ln_k<<<2048, 256, 0, stream>>>(xf, yf, g1 + lyr * 1024, be1 + lyr * 1024, xf, xb);

    if (tier <= 1)
      gemm_k<0, 128><<<dim3(32, 16), 256, 0, stream>>>(xb, w1P, 1024, 4096, 5, 1024,
          b1 + lyr * 4096, nullptr, nullptr, nullptr, nullptr, nullptr, nullptr, nullptr, hb);
    else
      gemm_k<1, 128><<<dim3(32, 16), 256, 0, stream>>>(xb, W1 + (size_t)lyr * 4194304, 1024, 4096, 5, 1024,
          b1 + lyr * 4096, nullptr, nullptr, nullptr, nullptr, nullptr, nullptr, nullptr, hb);

    if (tier <= 1)
      gemm_k<0, 64><<<dim3(16, 16, 2), 256, 0, stream>>>(hb, w2P, 4096, 1024, 4, 2048,
          b2 + lyr * 1024, nullptr, nullptr, nullptr, nullptr, nullptr, nullptr, yf, nullptr);
    else
      gemm_k<1, 64><<<dim3(16, 16, 2), 256, 0, stream>>>(hb, W2 + (size_t)lyr * 4194304, 4096, 1024, 4, 2048,
          b2 + lyr * 1024, nullptr, nullptr, nullptr, nullptr, nullptr, nullptr, yf, nullptr);

    ln_k<<<2048, 256, 0, stream>>>(xf, yf, g2 + lyr * 1024, be2 + lyr * 1024,
        (lyr == 3) ? out : xf, xb);
  }
}

// Round 4
// 834.862 us; speedup vs baseline: 1.5753x; 1.1502x over previous
//
#include <hip/hip_runtime.h>
#include <math.h>

typedef __attribute__((ext_vector_type(4))) float f32x4;
typedef __attribute__((ext_vector_type(8))) short s16x8;
typedef __attribute__((ext_vector_type(8))) unsigned short u16x8;
typedef __attribute__((ext_vector_type(4))) unsigned short u16x4;

#define DI __device__ __forceinline__

DI unsigned short f2bf(float f) {
  unsigned int u = __builtin_bit_cast(unsigned int, f);
  u = u + 0x7fffu + ((u >> 16) & 1u);
  return (unsigned short)(u >> 16);
}

DI void gload16(const unsigned short* g, unsigned short* l) {
  __builtin_amdgcn_global_load_lds(
      (const __attribute__((address_space(1))) void*)g,
      (__attribute__((address_space(3))) void*)l, 16, 0, 0);
}

// ---------------- weight fp32 -> bf16 (chunk/stride packing) ----------------
__global__ __launch_bounds__(256) void cvtw_k(const float* __restrict__ src,
    unsigned short* __restrict__ dst, int chunk, int dstStride, int total4)
{
  for (int i = blockIdx.x * 256 + threadIdx.x; i < total4; i += gridDim.x * 256) {
    int idx = i * 4;
    int blk = idx / chunk, off = idx - blk * chunk;
    f32x4 v = *reinterpret_cast<const f32x4*>(src + idx);
    u16x4 o = { f2bf(v[0]), f2bf(v[1]), f2bf(v[2]), f2bf(v[3]) };
    *reinterpret_cast<u16x4*>(dst + (size_t)blk * dstStride + off) = o;
  }
}

// ---------------- x -> xf (f32 master) + xb (bf16 mirror) ----------------
__global__ __launch_bounds__(256) void xinit_k(const float* __restrict__ x,
    float* __restrict__ xf, unsigned short* __restrict__ xb, int n4)
{
  for (int i = blockIdx.x * 256 + threadIdx.x; i < n4; i += gridDim.x * 256) {
    f32x4 v = *reinterpret_cast<const f32x4*>(x + (size_t)i * 4);
    *reinterpret_cast<f32x4*>(xf + (size_t)i * 4) = v;
    u16x4 o = { f2bf(v[0]), f2bf(v[1]), f2bf(v[2]), f2bf(v[3]) };
    *reinterpret_cast<u16x4*>(xb + (size_t)i * 4) = o;
  }
}

// ---------------- Ebar precompute: chunk sums then windowed sums ----------------
__global__ __launch_bounds__(64) void ebch_k(const float* __restrict__ rel,
    float* __restrict__ cs)
{
  int c = blockIdx.x, L = blockIdx.y, d = threadIdx.x;
  const float* p = rel + ((size_t)L * 2047 + c * 64) * 64 + d;
  int n = (c == 31) ? 63 : 64;
  float s = 0.f;
  for (int k = 0; k < n; ++k) s += p[(size_t)k * 64];
  cs[(L * 32 + c) * 64 + d] = s;
}

__global__ __launch_bounds__(64) void ebar_k(const float* __restrict__ rel,
    const float* __restrict__ cs, float* __restrict__ ebar4)
{
  int j = blockIdx.x, L = blockIdx.y, d = threadIdx.x;
  int s = 1023 - j, e = s + 1024;
  int c0 = (s + 63) >> 6, c1 = e >> 6;
  const float* rl = rel + (size_t)L * 2047 * 64;
  const float* cl = cs + L * 32 * 64;
  float acc = 0.f;
  for (int c = c0; c < c1; ++c) acc += cl[c * 64 + d];
  for (int t = s; t < c0 * 64; ++t) acc += rl[(size_t)t * 64 + d];
  for (int t = c1 * 64; t < e; ++t) acc += rl[(size_t)t * 64 + d];
  ebar4[((size_t)L * 1024 + j) * 64 + d] = acc * (1.f / 1024.f);
}

// ---------------- GEMM: C[m,n] = sum_k A[m,k]*B[n,k] + bias, fused epilogues ----
// K-loop: T3-minimum pipeline (stage t+1 BEFORE compute(t), single barrier/step,
// vmcnt(0) drain lands after compute) + 8-slot XOR swizzle (byte ^= (row&7)<<4)
// applied as pre-swizzled GLOBAL source (linear LDS dest, swizzled ds_read).
template<int BF32, int BN>
__global__ __launch_bounds__(256) void gemm_k(
    const unsigned short* __restrict__ A, const void* __restrict__ Bp,
    int K, int N, int mode, int kLen,
    const float* __restrict__ bias0, const float* __restrict__ bias1,
    const float* __restrict__ bias2, const float* __restrict__ ebar,
    unsigned short* __restrict__ qb, unsigned short* __restrict__ kb,
    unsigned short* __restrict__ vtb, float* __restrict__ yf,
    unsigned short* __restrict__ hb)
{
  constexpr int NI = BN / 32;
  constexpr int WC = BN / 2;
  constexpr int SMSZ = 2 * (128 + BN) * 64 > 128 * (BN + 8) ? 2 * (128 + BN) * 64 : 128 * (BN + 8);
  __shared__ __align__(16) unsigned short SM[SMSZ];
  auto As = reinterpret_cast<unsigned short(*)[64]>(SM);              // [2*128][64]
  auto Bs = reinterpret_cast<unsigned short(*)[64]>(SM + 2 * 128 * 64); // [2*BN][64]
  const int tid = threadIdx.x, l = tid & 63, w = tid >> 6;
  const int wr = w >> 1, wc = w & 1, lr = l & 15, lg = l >> 4;
  const int m0 = blockIdx.y * 128, n0 = blockIdx.x * BN;
  f32x4 acc[4][NI];
#pragma unroll
  for (int i = 0; i < 4; ++i)
#pragma unroll
    for (int j = 0; j < NI; ++j) acc[i][j] = f32x4{0.f, 0.f, 0.f, 0.f};

  const int kBeg = blockIdx.z * kLen, kEnd = kBeg + kLen;
  // pre-swizzled global source: colblock = (l&7) ^ (l>>3)  (row&7 == l>>3)
  const unsigned short* gaBase = A + (size_t)(m0 + (l >> 3)) * K + ((l & 7) ^ (l >> 3)) * 8;
  const unsigned short* gbBase = (BF32 == 0)
      ? (const unsigned short*)Bp + (size_t)(n0 + (l >> 3)) * K + ((l & 7) ^ (l >> 3)) * 8
      : nullptr;
  // swizzled read col offset (shorts): logical col ^ ((row&7)*8), row&7 == lr&7
  const int csw = (lr & 7) * 8;

  auto STAGE = [&](int cb, int k0) {
#pragma unroll
    for (int it = 0; it < 4; ++it) {
      int r0 = (w * 4 + it) * 8;
      gload16(gaBase + (size_t)r0 * K + k0, &As[cb * 128 + r0][0]);
    }
    if constexpr (BF32 == 0) {
#pragma unroll
      for (int it = 0; it < BN / 32; ++it) {
        int r0 = (w * (BN / 32) + it) * 8;
        gload16(gbBase + (size_t)r0 * K + k0, &Bs[cb * BN + r0][0]);
      }
    } else {
      const float* Bf = (const float*)Bp;
#pragma unroll
      for (int it = 0; it < BN / 16; ++it) {
        int lin = (it * 256 + tid) * 4, r = lin >> 6, c = lin & 63;
        f32x4 v = *reinterpret_cast<const f32x4*>(Bf + (size_t)(n0 + r) * K + k0 + c);
        u16x4 o = { f2bf(v[0]), f2bf(v[1]), f2bf(v[2]), f2bf(v[3]) };
        *reinterpret_cast<u16x4*>(&Bs[cb * BN + r][c ^ ((r & 7) << 3)]) = o;
      }
    }
  };

  STAGE(0, kBeg);
  __syncthreads();
  int cur = 0;
  for (int k0 = kBeg; k0 < kEnd; k0 += 64) {
    if (k0 + 64 < kEnd) STAGE(cur ^ 1, k0 + 64);
#pragma unroll
    for (int kk = 0; kk < 2; ++kk) {
      s16x8 af[4], bfr[NI];
#pragma unroll
      for (int mi = 0; mi < 4; ++mi)
        af[mi] = *reinterpret_cast<const s16x8*>(
            &As[cur * 128 + wr * 64 + mi * 16 + lr][(kk * 32 + lg * 8) ^ csw]);
#pragma unroll
      for (int ni = 0; ni < NI; ++ni)
        bfr[ni] = *reinterpret_cast<const s16x8*>(
            &Bs[cur * BN + wc * WC + ni * 16 + lr][(kk * 32 + lg * 8) ^ csw]);
#pragma unroll
      for (int mi = 0; mi < 4; ++mi)
#pragma unroll
        for (int ni = 0; ni < NI; ++ni)
          acc[mi][ni] = __builtin_amdgcn_mfma_f32_16x16x32_bf16(af[mi], bfr[ni], acc[mi][ni], 0, 0, 0);
    }
    __syncthreads();
    cur ^= 1;
  }

  if (mode <= 3) {
    int qtype, nbase;
    const float* bias;
    if (mode == 0) {
      qtype = n0 >> 10; nbase = n0 & 1023;
      bias = qtype == 0 ? bias0 : (qtype == 1 ? bias1 : bias2);
    } else { qtype = mode - 1; nbase = n0; bias = bias0; }
    if (qtype < 2) {
      unsigned short* dst = (qtype == 0) ? qb : kb;
#pragma unroll
      for (int mi = 0; mi < 4; ++mi)
#pragma unroll
        for (int ni = 0; ni < NI; ++ni) {
          int nin = nbase + wc * WC + ni * 16 + lr;
          int hh = nin >> 6, dh = nin & 63;
          float bv = bias[nin];
#pragma unroll
          for (int rr = 0; rr < 4; ++rr) {
            int m = m0 + wr * 64 + mi * 16 + lg * 4 + rr;
            int b = m >> 10, s = m & 1023;
            float v = acc[mi][ni][rr] + bv;
            if (qtype == 1) v = v * 0.125f + ebar[s * 64 + dh];
            dst[(size_t)(b * 16 + hh) * 65536 + (size_t)s * 64 + dh] = f2bf(v);
          }
        }
    } else {
      auto T = reinterpret_cast<unsigned short(*)[BN + 8]>(SM);
      __syncthreads();
#pragma unroll
      for (int mi = 0; mi < 4; ++mi)
#pragma unroll
        for (int ni = 0; ni < NI; ++ni) {
          int nl = wc * WC + ni * 16 + lr;
          float bv = bias[nbase + nl];
#pragma unroll
          for (int rr = 0; rr < 4; ++rr) {
            int ml = wr * 64 + mi * 16 + lg * 4 + rr;
            T[ml][nl] = f2bf(acc[mi][ni][rr] + bv);
          }
        }
      __syncthreads();
      int b = m0 >> 10, j0 = m0 & 1023;
#pragma unroll
      for (int lp = 0; lp < BN / 16; ++lp) {
        int dl = lp * 16 + (tid >> 4), jc = (tid & 15) * 8;
        u16x8 o;
#pragma unroll
        for (int e = 0; e < 8; ++e) o[e] = T[jc + e][dl];
        int nin = nbase + dl, hh = nin >> 6, dh = nin & 63;
        *reinterpret_cast<u16x8*>(vtb + (size_t)(b * 16 + hh) * 65536 + (size_t)dh * 1024 + j0 + jc) = o;
      }
    }
  } else {
    float* yfp = yf + (size_t)blockIdx.z * 2097152;
#pragma unroll
    for (int mi = 0; mi < 4; ++mi)
#pragma unroll
      for (int ni = 0; ni < NI; ++ni) {
        int nn = n0 + wc * WC + ni * 16 + lr;
        float bv = (blockIdx.z == 0) ? bias0[nn] : 0.f;
#pragma unroll
        for (int rr = 0; rr < 4; ++rr) {
          int m = m0 + wr * 64 + mi * 16 + lg * 4 + rr;
          float v = acc[mi][ni][rr] + bv;
          if (mode == 4) yfp[(size_t)m * N + nn] = v;
          else hb[(size_t)m * N + nn] = f2bf(0.5f * v * (1.f + erff(v * 0.70710678118654752f)));
        }
      }
  }
}

// ---------------- flash attention v3: LDS-staged, prefetch, no-max softmax,
//                  KV-split x2, XCD-bijective grid ----------------
__global__ __launch_bounds__(256, 4) void attn_k(const unsigned short* __restrict__ qb,
    const unsigned short* __restrict__ kb, const unsigned short* __restrict__ vtb,
    float* __restrict__ opart, float* __restrict__ lpart)
{
  __shared__ __align__(16) unsigned short Ks[2][64][72];
  __shared__ __align__(16) unsigned short Vs[64][72];
  __shared__ __align__(16) unsigned short Pl[4][16][72];
  const int id = blockIdx.x;
  const int xcd = id & 7, sub = id >> 3;
  const int bh = xcd * 4 + (sub >> 5);
  const int rest = sub & 31;
  const int tq = rest >> 1, half = rest & 1;
  const int tid = threadIdx.x, l = tid & 63, w = tid >> 6;
  const int lr = l & 15, lg = l >> 4;
  const int jt0 = half * 8;

  const unsigned short* Kb = kb + (size_t)bh * 65536;
  const unsigned short* Vb = vtb + (size_t)bh * 65536;

  const unsigned short* Qp = qb + (size_t)bh * 65536 +
      (size_t)(tq * 64 + w * 16 + lr) * 64 + lg * 8;
  s16x8 qf0 = *reinterpret_cast<const s16x8*>(Qp);
  s16x8 qf1 = *reinterpret_cast<const s16x8*>(Qp + 32);

  const int srow = tid >> 2, scol = (tid & 3) * 16;
  const unsigned short* kg = Kb + (size_t)srow * 64 + scol + (size_t)jt0 * 4096;
  const unsigned short* vg = Vb + (size_t)srow * 1024 + scol + (size_t)jt0 * 64;

  u16x8 krg[2][2], vrg[2][2];
  f32x4 oacc[4];
#pragma unroll
  for (int di = 0; di < 4; ++di) oacc[di] = f32x4{0.f, 0.f, 0.f, 0.f};
  float Lp[4] = { 0.f, 0.f, 0.f, 0.f };

  krg[0][0] = *reinterpret_cast<const u16x8*>(kg);
  krg[0][1] = *reinterpret_cast<const u16x8*>(kg + 8);
  vrg[0][0] = *reinterpret_cast<const u16x8*>(vg);
  vrg[0][1] = *reinterpret_cast<const u16x8*>(vg + 8);
  *reinterpret_cast<u16x8*>(&Ks[0][srow][scol]) = krg[0][0];
  *reinterpret_cast<u16x8*>(&Ks[0][srow][scol + 8]) = krg[0][1];
  krg[1][0] = *reinterpret_cast<const u16x8*>(kg + 4096);
  krg[1][1] = *reinterpret_cast<const u16x8*>(kg + 4096 + 8);
  vrg[1][0] = *reinterpret_cast<const u16x8*>(vg + 64);
  vrg[1][1] = *reinterpret_cast<const u16x8*>(vg + 64 + 8);

#pragma unroll
  for (int it = 0; it < 8; ++it) {
    const int buf = it & 1, nxt = buf ^ 1;
    asm volatile("s_waitcnt lgkmcnt(0)" ::: "memory");
    __builtin_amdgcn_s_barrier();
    __builtin_amdgcn_sched_barrier(0);
    *reinterpret_cast<u16x8*>(&Vs[srow][scol]) = vrg[buf][0];
    *reinterpret_cast<u16x8*>(&Vs[srow][scol + 8]) = vrg[buf][1];
    f32x4 sacc[4];
#pragma unroll
    for (int ni = 0; ni < 4; ++ni) sacc[ni] = f32x4{0.f, 0.f, 0.f, 0.f};
#pragma unroll
    for (int kk = 0; kk < 2; ++kk) {
      s16x8 qq = kk ? qf1 : qf0;
#pragma unroll
      for (int ni = 0; ni < 4; ++ni) {
        s16x8 kf = *reinterpret_cast<const s16x8*>(&Ks[buf][ni * 16 + lr][kk * 32 + lg * 8]);
        sacc[ni] = __builtin_amdgcn_mfma_f32_16x16x32_bf16(qq, kf, sacc[ni], 0, 0, 0);
      }
    }
#pragma unroll
    for (int r = 0; r < 4; ++r) {
#pragma unroll
      for (int ni = 0; ni < 4; ++ni) {
        float p = __expf(fminf(sacc[ni][r], 80.f));
        Lp[r] += p;
        Pl[w][lg * 4 + r][ni * 16 + lr] = f2bf(p);
      }
    }
    asm volatile("s_waitcnt lgkmcnt(0)" ::: "memory");
    __builtin_amdgcn_s_barrier();
    __builtin_amdgcn_sched_barrier(0);
#pragma unroll
    for (int kk = 0; kk < 2; ++kk) {
      s16x8 pa = *reinterpret_cast<const s16x8*>(&Pl[w][lr][kk * 32 + lg * 8]);
#pragma unroll
      for (int di = 0; di < 4; ++di) {
        s16x8 vf = *reinterpret_cast<const s16x8*>(&Vs[di * 16 + lr][kk * 32 + lg * 8]);
        oacc[di] = __builtin_amdgcn_mfma_f32_16x16x32_bf16(pa, vf, oacc[di], 0, 0, 0);
      }
    }
    if (it < 7) {
      *reinterpret_cast<u16x8*>(&Ks[nxt][srow][scol]) = krg[nxt][0];
      *reinterpret_cast<u16x8*>(&Ks[nxt][srow][scol + 8]) = krg[nxt][1];
    }
    if (it < 6) {
      const unsigned short* kp = kg + (size_t)(it + 2) * 4096;
      const unsigned short* vp = vg + (size_t)(it + 2) * 64;
      krg[buf][0] = *reinterpret_cast<const u16x8*>(kp);
      krg[buf][1] = *reinterpret_cast<const u16x8*>(kp + 8);
      vrg[buf][0] = *reinterpret_cast<const u16x8*>(vp);
      vrg[buf][1] = *reinterpret_cast<const u16x8*>(vp + 8);
    }
  }

#pragma unroll
  for (int r = 0; r < 4; ++r) {
#pragma unroll
    for (int xm = 1; xm < 16; xm <<= 1) Lp[r] += __shfl_xor(Lp[r], xm);
  }
  const size_t obase = ((size_t)(half * 32 + bh) * 1024 + tq * 64 + w * 16);
#pragma unroll
  for (int r = 0; r < 4; ++r) {
    int qrow = lg * 4 + r;
#pragma unroll
    for (int di = 0; di < 4; ++di)
      opart[(obase + qrow) * 64 + di * 16 + lr] = oacc[di][r];
    if (lr == 0) lpart[obase + qrow] = Lp[r];
  }
}

// ---------------- merge KV-split partials -> ctx (bf16) ----------------
__global__ __launch_bounds__(256) void amrg_k(const float* __restrict__ opart,
    const float* __restrict__ lpart, unsigned short* __restrict__ ctx)
{
  int e4 = blockIdx.x * 256 + threadIdx.x;
  int d4 = e4 & 15, q = (e4 >> 4) & 1023, bh = e4 >> 14;
  size_t po = ((size_t)bh * 1024 + q) * 64 + d4 * 4;
  f32x4 o0 = *reinterpret_cast<const f32x4*>(opart + po);
  f32x4 o1 = *reinterpret_cast<const f32x4*>(opart + 2097152 + po);
  float linv = 1.f / (lpart[bh * 1024 + q] + lpart[32768 + bh * 1024 + q]);
  int b = bh >> 4, h = bh & 15;
  u16x4 o;
#pragma unroll
  for (int e = 0; e < 4; ++e) o[e] = f2bf((o0[e] + o1[e]) * linv);
  *reinterpret_cast<u16x4*>(ctx + (size_t)(b * 1024 + q) * 1024 + h * 64 + d4 * 4) = o;
}

// ---------------- LayerNorm(xf + yf0 + yf1) -> outf (f32) + outb (bf16) ----------------
__global__ __launch_bounds__(256) void ln_k(const float* __restrict__ xf,
    const float* __restrict__ yf, const float* __restrict__ g,
    const float* __restrict__ be, float* __restrict__ outf,
    unsigned short* __restrict__ outb)
{
  int row = blockIdx.x, tid = threadIdx.x, l = tid & 63, w = tid >> 6;
  size_t base = (size_t)row * 1024 + tid * 4;
  f32x4 v = *reinterpret_cast<const f32x4*>(xf + base);
  f32x4 y0 = *reinterpret_cast<const f32x4*>(yf + base);
  f32x4 y1 = *reinterpret_cast<const f32x4*>(yf + 2097152 + base);
  v = v + y0 + y1;
  float s = v[0] + v[1] + v[2] + v[3];
  float q = v[0] * v[0] + v[1] * v[1] + v[2] * v[2] + v[3] * v[3];
#pragma unroll
  for (int off = 1; off < 64; off <<= 1) { s += __shfl_xor(s, off); q += __shfl_xor(q, off); }
  __shared__ float ss[4], qq[4];
  if (l == 0) { ss[w] = s; qq[w] = q; }
  __syncthreads();
  s = ss[0] + ss[1] + ss[2] + ss[3];
  q = qq[0] + qq[1] + qq[2] + qq[3];
  float m = s * (1.f / 1024.f);
  float var = q * (1.f / 1024.f) - m * m;
  float rs = rsqrtf(var + 1e-5f);
  f32x4 gv = *reinterpret_cast<const f32x4*>(g + tid * 4);
  f32x4 bv = *reinterpret_cast<const f32x4*>(be + tid * 4);
  f32x4 o; u16x4 ob;
#pragma unroll
  for (int e = 0; e < 4; ++e) { o[e] = (v[e] - m) * rs * gv[e] + bv[e]; ob[e] = f2bf(o[e]); }
  *reinterpret_cast<f32x4*>(outf + base) = o;
  *reinterpret_cast<u16x4*>(outb + base) = ob;
}

// ---------------- host ----------------
extern "C" void kernel_launch(void* const* d_in, const int* in_sizes, int n_in,
                              void* d_out, int out_size, void* d_ws, size_t ws_size,
                              hipStream_t stream)
{
  (void)in_sizes; (void)n_in; (void)out_size;
  const float* x   = (const float*)d_in[0];
  const float* Wq  = (const float*)d_in[1];
  const float* bq  = (const float*)d_in[2];
  const float* Wk  = (const float*)d_in[3];
  const float* bk  = (const float*)d_in[4];
  const float* Wv  = (const float*)d_in[5];
  const float* bv  = (const float*)d_in[6];
  const float* Wo  = (const float*)d_in[7];
  const float* bo  = (const float*)d_in[8];
  const float* rel = (const float*)d_in[9];
  const float* W1  = (const float*)d_in[10];
  const float* b1  = (const float*)d_in[11];
  const float* W2  = (const float*)d_in[12];
  const float* b2  = (const float*)d_in[13];
  const float* g1  = (const float*)d_in[14];
  const float* be1 = (const float*)d_in[15];
  const float* g2  = (const float*)d_in[16];
  const float* be2 = (const float*)d_in[17];
  float* out = (float*)d_out;
  char* ws = (char*)d_ws;

  const size_t OFF_XF = 0, OFF_YF = 8388608, OFF_XB = 25165824, OFF_QB = 29360128,
      OFF_KB = 33554432, OFF_VT = 37748736, OFF_CT = 41943040,
      OFF_HB = 46137344, OFF_LP = 62914560, OFF_EB = 63176704,
      OFF_CS = 64225280, OFF_W = 64258048;
  const size_t NEED_A = OFF_W + 100663296, NEED_B = OFF_W + 25165824;

  float* xf = (float*)(ws + OFF_XF);
  float* yf = (float*)(ws + OFF_YF);
  unsigned short* xb  = (unsigned short*)(ws + OFF_XB);
  unsigned short* qbp = (unsigned short*)(ws + OFF_QB);
  unsigned short* kbp = (unsigned short*)(ws + OFF_KB);
  unsigned short* vtp = (unsigned short*)(ws + OFF_VT);
  unsigned short* ctx = (unsigned short*)(ws + OFF_CT);
  unsigned short* hb  = (unsigned short*)(ws + OFF_HB);
  float* opart = (float*)(ws + OFF_HB);
  float* lpart = (float*)(ws + OFF_LP);
  float* ebar4 = (float*)(ws + OFF_EB);
  float* csum  = (float*)(ws + OFF_CS);
  unsigned short* wb = (unsigned short*)(ws + OFF_W);

  const int tier = (ws_size >= NEED_A) ? 0 : (ws_size >= NEED_B ? 1 : 2);

  if (tier == 0) {
    cvtw_k<<<2048, 256, 0, stream>>>(Wq, wb,           1048576, 3145728, 1048576);
    cvtw_k<<<2048, 256, 0, stream>>>(Wk, wb + 1048576, 1048576, 3145728, 1048576);
    cvtw_k<<<2048, 256, 0, stream>>>(Wv, wb + 2097152, 1048576, 3145728, 1048576);
    cvtw_k<<<2048, 256, 0, stream>>>(Wo, wb + 12582912, 1048576, 1048576, 1048576);
    cvtw_k<<<2048, 256, 0, stream>>>(W1, wb + 16777216, 4194304, 4194304, 4194304);
    cvtw_k<<<2048, 256, 0, stream>>>(W2, wb + 33554432, 4194304, 4194304, 4194304);
  }
  xinit_k<<<2048, 256, 0, stream>>>(x, xf, xb, 524288);
  ebch_k<<<dim3(32, 4), 64, 0, stream>>>(rel, csum);
  ebar_k<<<dim3(1024, 4), 64, 0, stream>>>(rel, csum, ebar4);

  for (int lyr = 0; lyr < 4; ++lyr) {
    const float* eb = ebar4 + (size_t)lyr * 65536;
    const unsigned short *wqkvP, *woP, *w1P, *w2P;
    if (tier == 0) {
      wqkvP = wb + (size_t)lyr * 3145728;
      woP   = wb + 12582912 + (size_t)lyr * 1048576;
      w1P   = wb + 16777216 + (size_t)lyr * 4194304;
      w2P   = wb + 33554432 + (size_t)lyr * 4194304;
    } else if (tier == 1) {
      wqkvP = wb; woP = wb + 3145728; w1P = wb + 4194304; w2P = wb + 8388608;
      cvtw_k<<<1024, 256, 0, stream>>>(Wq + (size_t)lyr * 1048576, wb,           1 << 30, 0, 262144);
      cvtw_k<<<1024, 256, 0, stream>>>(Wk + (size_t)lyr * 1048576, wb + 1048576, 1 << 30, 0, 262144);
      cvtw_k<<<1024, 256, 0, stream>>>(Wv + (size_t)lyr * 1048576, wb + 2097152, 1 << 30, 0, 262144);
      cvtw_k<<<1024, 256, 0, stream>>>(Wo + (size_t)lyr * 1048576, wb + 3145728, 1 << 30, 0, 262144);
      cvtw_k<<<2048, 256, 0, stream>>>(W1 + (size_t)lyr * 4194304, wb + 4194304, 1 << 30, 0, 1048576);
      cvtw_k<<<2048, 256, 0, stream>>>(W2 + (size_t)lyr * 4194304, wb + 8388608, 1 << 30, 0, 1048576);
    } else { wqkvP = woP = w1P = w2P = nullptr; }

    if (tier <= 1) {
      gemm_k<0, 64><<<dim3(48, 16), 256, 0, stream>>>(xb, wqkvP, 1024, 3072, 0, 1024,
          bq + lyr * 1024, bk + lyr * 1024, bv + lyr * 1024, eb, qbp, kbp, vtp, nullptr, nullptr);
    } else {
      gemm_k<1, 128><<<dim3(8, 16), 256, 0, stream>>>(xb, Wq + (size_t)lyr * 1048576, 1024, 1024, 1, 1024,
          bq + lyr * 1024, nullptr, nullptr, eb, qbp, kbp, vtp, nullptr, nullptr);
      gemm_k<1, 128><<<dim3(8, 16), 256, 0, stream>>>(xb, Wk + (size_t)lyr * 1048576, 1024, 1024, 2, 1024,
          bk + lyr * 1024, nullptr, nullptr, eb, qbp, kbp, vtp, nullptr, nullptr);
      gemm_k<1, 128><<<dim3(8, 16), 256, 0, stream>>>(xb, Wv + (size_t)lyr * 1048576, 1024, 1024, 3, 1024,
          bv + lyr * 1024, nullptr, nullptr, eb, qbp, kbp, vtp, nullptr, nullptr);
    }

    attn_k<<<1024, 256, 0, stream>>>(qbp, kbp, vtp, opart, lpart);
    amrg_k<<<2048, 256, 0, stream>>>(opart, lpart, ctx);

    if (tier <= 1)
      gemm_k<0, 64><<<dim3(16, 16, 2), 256, 0, stream>>>(ctx, woP, 1024, 1024, 4, 512,
          bo + lyr * 1024, nullptr, nullptr, nullptr, nullptr, nullptr, nullptr, yf, nullptr);
    else
      gemm_k<1, 64><<<dim3(16, 16, 2), 256, 0, stream>>>(ctx, Wo + (size_t)lyr * 1048576, 1024, 1024, 4, 512,
          bo + lyr * 1024, nullptr, nullptr, nullptr, nullptr, nullptr, nullptr, yf, nullptr);

    ln_k<<<2048, 256, 0, stream>>>(xf, yf, g1 + lyr * 1024, be1 + lyr * 1024, xf, xb);

    if (tier <= 1)
      gemm_k<0, 128><<<dim3(32, 16), 256, 0, stream>>>(xb, w1P, 1024, 4096, 5, 1024,
          b1 + lyr * 4096, nullptr, nullptr, nullptr, nullptr, nullptr, nullptr, nullptr, hb);
    else
      gemm_k<1, 128><<<dim3(32, 16), 256, 0, stream>>>(xb, W1 + (size_t)lyr * 4194304, 1024, 4096, 5, 1024,
          b1 + lyr * 4096, nullptr, nullptr, nullptr, nullptr, nullptr, nullptr, nullptr, hb);

    if (tier <= 1)
      gemm_k<0, 64><<<dim3(16, 16, 2), 256, 0, stream>>>(hb, w2P, 4096, 1024, 4, 2048,
          b2 + lyr * 1024, nullptr, nullptr, nullptr, nullptr, nullptr, nullptr, yf, nullptr);
    else
      gemm_k<1, 64><<<dim3(16, 16, 2), 256, 0, stream>>>(hb, W2 + (size_t)lyr * 4194304, 4096, 1024, 4, 2048,
          b2 + lyr * 1024, nullptr, nullptr, nullptr, nullptr, nullptr, nullptr, yf, nullptr);

    ln_k<<<2048, 256, 0, stream>>>(xf, yf, g2 + lyr * 1024, be2 + lyr * 1024,
        (lyr == 3) ? out : xf, xb);
  }
}